// Round 5
// baseline (2133.466 us; speedup 1.0000x reference)
//

#include <hip/hip_runtime.h>
#include <hip/hip_bf16.h>

// Round 5: ultra-conservative full implementation.
// Evidence so far: d_out has never been touched by our code (error always
// exactly max|ref|), so prior builds likely never ran. This version sticks to
// stub-sanctioned constructs only: plain kernels, hip_bf16.h, no templates,
// no lambdas, no shuffles, no runtime API calls beyond kernel launches.

typedef __hip_bfloat16 bf16;

static __device__ float bf2f(bf16 v){ return __bfloat162float(v); }

// float loader over maybe-bf16 / maybe-f32 data (flag 1 = bf16)
static __device__ float ldany(const void* p, long long i, int isbf){
  if (isbf) return __bfloat162float(((const bf16*)p)[i]);
  return ((const float*)p)[i];
}
// int loader over maybe-int64 / maybe-int32 data (flag 1 = int64)
static __device__ int ldidx(const void* p, long long i, int is64){
  if (is64) return (int)((const long long*)p)[i];
  return ((const int*)p)[i];
}

// keep the stub's symbol, never launched
__global__ void Petri_Cheb_GNN_76639396430230_kernel(){}

// ---- utility ---------------------------------------------------------------

__global__ void k_zero(int* p, int n){
  int i = blockIdx.x*256 + threadIdx.x;
  if (i < n) p[i] = 0;
}

// flags[0] = indices are int64; flags[1] = float tensors are bf16
__global__ void k_detect(const void* ei, const void* x, int N, int* flags){
  if (threadIdx.x != 0 || blockIdx.x != 0) return;
  const int* e32 = (const int*)ei;
  int is64 = 1;
  for (int t = 0; t < 64; t++){
    int lo = e32[2*t], hi = e32[2*t+1];
    if (!(hi == 0 && lo >= 0 && lo < N)){ is64 = 0; break; }
  }
  flags[0] = is64;
  const unsigned short* xh = (const unsigned short*)x;
  int isbf = 1;
  for (int t = 0; t < 128; t++){
    unsigned u = ((unsigned)xh[t]) << 16;
    float v;
    __builtin_memcpy(&v, &u, 4);
    if (!(v == v) || fabsf(v) > 64.f){ isbf = 0; break; }
  }
  flags[1] = isbf;
}

// convert maybe-bf16 tensor to f32 scratch
__global__ void k_cvt(const void* src, float* dst, int n, const int* flags){
  int i = blockIdx.x*256 + threadIdx.x;
  if (i < n) dst[i] = ldany(src, i, flags[1]);
}

// convert input x to bf16 feature buffer
__global__ void k_x2a(const void* x, bf16* a, int n, const int* flags){
  int i = blockIdx.x*256 + threadIdx.x;
  if (i < n) a[i] = __float2bfloat16(ldany(x, i, flags[1]));
}

// ---- CSR build -------------------------------------------------------------

__global__ void k_deg_cnt(const void* ei, const float* ewf, float* deg, int* cnt,
                          const int* flags, int E, int N){
  int e = blockIdx.x*256 + threadIdx.x;
  if (e >= E) return;
  int is64 = flags[0];
  int s = ldidx(ei, e, is64);
  int t = ldidx(ei, (long long)E + e, is64);
  if (s >= 0 && s < N) atomicAdd(&deg[s], ewf[e]);
  if (t >= 0 && t < N) atomicAdd(&cnt[t], 1);
}

__global__ void k_dis(float* deg, int N){
  int i = blockIdx.x*256 + threadIdx.x;
  if (i >= N) return;
  float d = deg[i];
  deg[i] = (d > 0.f) ? rsqrtf(d) : 0.f;   // deg now holds D^{-1/2}
}

__global__ void k_block_sums(const int* cnt, int* bsum, int N){
  __shared__ int s[256];
  int t = threadIdx.x;
  int i = blockIdx.x*256 + t;
  s[t] = (i < N) ? cnt[i] : 0;
  __syncthreads();
  for (int o = 128; o > 0; o >>= 1){
    if (t < o) s[t] += s[t + o];
    __syncthreads();
  }
  if (t == 0) bsum[blockIdx.x] = s[0];
}

__global__ void k_scan_partials(int* bsum, int nb){
  __shared__ int s[512];
  int t = threadIdx.x;
  s[t] = (t < nb) ? bsum[t] : 0;
  __syncthreads();
  for (int o = 1; o < 512; o <<= 1){
    int v = (t >= o) ? s[t - o] : 0;
    __syncthreads();
    s[t] += v;
    __syncthreads();
  }
  if (t < nb) bsum[t] = (t == 0) ? 0 : s[t - 1];   // exclusive prefix
}

__global__ void k_scan_final(const int* cnt, const int* bsum, int* rowptr, int N, int E){
  __shared__ int s[256];
  int t = threadIdx.x;
  int i = blockIdx.x*256 + t;
  int v = (i < N) ? cnt[i] : 0;
  s[t] = v;
  __syncthreads();
  for (int o = 1; o < 256; o <<= 1){
    int u = (t >= o) ? s[t - o] : 0;
    __syncthreads();
    s[t] += u;
    __syncthreads();
  }
  if (i < N) rowptr[i] = s[t] - v + bsum[blockIdx.x];
  if (i == 0) rowptr[N] = E;
}

__global__ void k_copy_int(const int* a, int* b, int n){
  int i = blockIdx.x*256 + threadIdx.x;
  if (i < n) b[i] = a[i];
}

__global__ void k_fill(const void* ei, const float* ewf, const float* dis, int* nxt,
                       int* col, float* wv, const int* flags, int E, int N){
  int e = blockIdx.x*256 + threadIdx.x;
  if (e >= E) return;
  int is64 = flags[0];
  int s = ldidx(ei, e, is64);
  int t = ldidx(ei, (long long)E + e, is64);
  if (s < 0 || s >= N || t < 0 || t >= N) return;
  float w = -dis[s] * ewf[e] * dis[t];
  int p = atomicAdd(&nxt[t], 1);
  if (p >= 0 && p < E){ col[p] = s; wv[p] = w; }
}

// ---- propagation: hout[v][f] = alpha*sum_e wv[e]*hin[col[e]][f] (- sub[v][f])

__global__ void k_prop(const int* rowptr, const int* col, const float* wv,
                       const bf16* hin, const bf16* sub, bf16* hout,
                       float alpha, int N){
  int v = blockIdx.x*4 + (threadIdx.x >> 6);
  if (v >= N) return;
  int lane = threadIdx.x & 63;
  int beg = rowptr[v], end = rowptr[v+1];
  float a0 = 0.f, a1 = 0.f;
  int e = beg;
  for (; e + 2 <= end; e += 2){
    int   s0 = col[e],   s1 = col[e+1];
    float w0 = wv[e],    w1 = wv[e+1];
    float h0 = bf2f(hin[(long long)s0*64 + lane]);
    float h1 = bf2f(hin[(long long)s1*64 + lane]);
    a0 = fmaf(w0, h0, a0);
    a1 = fmaf(w1, h1, a1);
  }
  if (e < end) a0 = fmaf(wv[e], bf2f(hin[(long long)col[e]*64 + lane]), a0);
  float r = alpha * (a0 + a1);
  if (sub) r -= bf2f(sub[(long long)v*64 + lane]);
  hout[(long long)v*64 + lane] = __float2bfloat16(r);
}

// ---- fused 3-matmul: out[n][h] = bias[h] + sum_c sum_k Tc[n][k]*W[c][k][h]
// 64 nodes x 64 outputs per block, 256 threads, 4x4 micro-tile.
// out aliases T0: safe, each block reads/writes only its own 64 rows and all
// reads complete (staged into LDS) before the final store.

__global__ void k_mm3(const bf16* T0, const bf16* T1, const bf16* T2,
                      const float* W, const float* bias, bf16* out, int N){
  __shared__ float Tn[64*65];
  __shared__ float Wc[64*64];
  int tid = threadIdx.x;
  int tx = tid & 15, ty = tid >> 4;
  int n0 = blockIdx.x * 64;
  float acc[4][4];
  for (int i = 0; i < 4; i++)
    for (int j = 0; j < 4; j++) acc[i][j] = 0.f;
  for (int c = 0; c < 3; c++){
    const bf16* Tm = (c == 0) ? T0 : ((c == 1) ? T1 : T2);
    for (int j = 0; j < 16; j++){
      int idx = tid + j*256;
      int r = idx >> 6, kk = idx & 63;
      int row = n0 + r;
      Tn[r*65 + kk] = (row < N) ? bf2f(Tm[(long long)row*64 + kk]) : 0.f;
      Wc[idx] = W[c*4096 + idx];
    }
    __syncthreads();
    for (int k = 0; k < 64; k++){
      float a0 = Tn[(ty*4+0)*65 + k];
      float a1 = Tn[(ty*4+1)*65 + k];
      float a2 = Tn[(ty*4+2)*65 + k];
      float a3 = Tn[(ty*4+3)*65 + k];
      float b0 = Wc[k*64 + tx*4 + 0];
      float b1 = Wc[k*64 + tx*4 + 1];
      float b2 = Wc[k*64 + tx*4 + 2];
      float b3 = Wc[k*64 + tx*4 + 3];
      acc[0][0] = fmaf(a0,b0,acc[0][0]); acc[0][1] = fmaf(a0,b1,acc[0][1]);
      acc[0][2] = fmaf(a0,b2,acc[0][2]); acc[0][3] = fmaf(a0,b3,acc[0][3]);
      acc[1][0] = fmaf(a1,b0,acc[1][0]); acc[1][1] = fmaf(a1,b1,acc[1][1]);
      acc[1][2] = fmaf(a1,b2,acc[1][2]); acc[1][3] = fmaf(a1,b3,acc[1][3]);
      acc[2][0] = fmaf(a2,b0,acc[2][0]); acc[2][1] = fmaf(a2,b1,acc[2][1]);
      acc[2][2] = fmaf(a2,b2,acc[2][2]); acc[2][3] = fmaf(a2,b3,acc[2][3]);
      acc[3][0] = fmaf(a3,b0,acc[3][0]); acc[3][1] = fmaf(a3,b1,acc[3][1]);
      acc[3][2] = fmaf(a3,b2,acc[3][2]); acc[3][3] = fmaf(a3,b3,acc[3][3]);
    }
    __syncthreads();
  }
  for (int i2 = 0; i2 < 4; i2++){
    int row = n0 + ty*4 + i2;
    if (row < N){
      for (int j = 0; j < 4; j++)
        out[(long long)row*64 + tx*4 + j] = __float2bfloat16(acc[i2][j] + bias[tx*4 + j]);
    }
  }
}

// ---- readout + pooling (LDS reductions only, no shuffles) ------------------
// 4 nodes per 256-thread block; wave per node; lane = (feature pair half, h)

__global__ void k_readout(const bf16* y, const void* batch,
                          const float* wr1, const float* br1,
                          const float* wr2, const float* br2,
                          float* gsum, int* gcnt, const int* flags, int N, int G){
  __shared__ float W1[2048];
  __shared__ float red[256];
  int tid = threadIdx.x;
  for (int j = tid; j < 2048; j += 256) W1[j] = wr1[j];
  __syncthreads();
  int v    = blockIdx.x*4 + (tid >> 6);
  int lane = tid & 63;
  int h    = lane & 31;     // hidden unit 0..31
  int p0   = lane >> 5;     // which half of the 64 input dims
  float acc = 0.f;
  if (v < N){
    for (int i = 0; i < 32; i++)
      acc = fmaf(bf2f(y[(long long)v*64 + p0*32 + i]), W1[(p0*32 + i)*32 + h], acc);
  }
  red[tid] = acc;
  __syncthreads();
  // combine the two halves -> full dot for feature h, then relu, then *wr2
  float rp = 0.f;
  if (lane < 32){
    int base = tid & ~63;
    float dot = red[base + lane] + red[base + lane + 32];
    float hr = dot + br1[lane];
    if (hr < 0.f) hr = 0.f;
    rp = hr * wr2[lane];
  }
  __syncthreads();
  red[tid] = rp;
  __syncthreads();
  for (int o = 16; o > 0; o >>= 1){
    if (lane < o) red[tid] += red[tid + o];
    __syncthreads();
  }
  if (lane == 0 && v < N){
    float r = red[tid] + br2[0];
    int b = ldidx(batch, v, flags[0]);
    if (b >= 0 && b < G){
      atomicAdd(&gsum[b], r);
      atomicAdd(&gcnt[b], 1);
    }
  }
}

// write result; if all sums are exactly zero (impossible for a live run),
// emit 30000 so a dead pipeline is distinguishable from "never ran".
__global__ void k_finalize(const float* gsum, const int* gcnt, void* out, int G,
                           const int* flags){
  __shared__ float mx;
  if (threadIdx.x == 0){
    float m = 0.f;
    for (int g = 0; g < G; g++){
      float a = gsum[g]; if (a < 0.f) a = -a;
      if (a > m) m = a;
    }
    mx = m;
  }
  __syncthreads();
  int g = threadIdx.x;
  if (g >= G) return;
  float c = (float)gcnt[g];
  if (c < 1.f) c = 1.f;
  float val = (mx > 0.f) ? (gsum[g] / c) : 30000.f;
  if (flags[1]) ((bf16*)out)[g] = __float2bfloat16(val);
  else          ((float*)out)[g] = val;
}

// ---- launch ----------------------------------------------------------------

extern "C" void kernel_launch(void* const* d_in, const int* in_sizes, int n_in,
                              void* d_out, int out_size, void* d_ws, size_t ws_size,
                              hipStream_t stream){
  const void* x     = d_in[0];
  const void* ei    = d_in[1];
  const void* ew    = d_in[2];
  const void* batch = d_in[3];
  const void* wl    = d_in[4];
  const void* bl    = d_in[5];
  const void* wr1   = d_in[6];
  const void* br1   = d_in[7];
  const void* wr2   = d_in[8];
  const void* br2   = d_in[9];
  (void)n_in; (void)ws_size;

  int N = in_sizes[3];
  int E = in_sizes[2];
  int G = out_size;

  // workspace layout (256B aligned), bf16 features: ~59 MB total
  char* p = (char*)d_ws;
  int* flags = (int*)p;                 p += 256;
  float* ewf = (float*)p;               p += (((size_t)E*4 + 255) / 256) * 256;
  float* wf  = (float*)p;               p += (51712*4 + 255) / 256 * 256;
  int* col   = (int*)p;                 p += (((size_t)E*4 + 255) / 256) * 256;
  float* wv  = (float*)p;               p += (((size_t)E*4 + 255) / 256) * 256;
  int* rowptr= (int*)p;                 p += (((size_t)(N+1)*4 + 255) / 256) * 256;
  int* cnt   = (int*)p;                 p += (((size_t)N*4 + 255) / 256) * 256;
  float* deg = (float*)p;               p += (((size_t)N*4 + 255) / 256) * 256;
  int* bsum  = (int*)p;                 p += 4096;
  float* gsum= (float*)p;               p += 1024;
  int* gcnt  = (int*)p;                 p += 1024;
  bf16* A    = (bf16*)p;                p += (((size_t)N*64*2 + 255) / 256) * 256;
  bf16* B    = (bf16*)p;                p += (((size_t)N*64*2 + 255) / 256) * 256;
  bf16* C    = (bf16*)p;                p += (((size_t)N*64*2 + 255) / 256) * 256;

  float* wlf  = wf;           // 49152
  float* blf  = wlf + 49152;  // 256
  float* wr1f = blf + 256;    // 2048
  float* br1f = wr1f + 2048;  // 32
  float* wr2f = br1f + 32;    // 32
  float* br2f = wr2f + 32;    // 1

  int ebl = (E + 255)/256;
  int nbl = (N + 255)/256;

  k_detect<<<1, 64, 0, stream>>>(ei, x, N, flags);
  k_zero<<<nbl, 256, 0, stream>>>((int*)deg, N);
  k_zero<<<nbl, 256, 0, stream>>>(cnt, N);
  k_zero<<<1, 256, 0, stream>>>((int*)gsum, 256);
  k_zero<<<1, 256, 0, stream>>>(gcnt, 256);

  k_cvt<<<ebl, 256, 0, stream>>>(ew, ewf, E, flags);
  k_cvt<<<192, 256, 0, stream>>>(wl, wlf, 49152, flags);
  k_cvt<<<1, 256, 0, stream>>>(bl, blf, 256, flags);
  k_cvt<<<8, 256, 0, stream>>>(wr1, wr1f, 2048, flags);
  k_cvt<<<1, 256, 0, stream>>>(br1, br1f, 32, flags);
  k_cvt<<<1, 256, 0, stream>>>(wr2, wr2f, 32, flags);
  k_cvt<<<1, 256, 0, stream>>>(br2, br2f, 1, flags);

  k_deg_cnt<<<ebl, 256, 0, stream>>>(ei, ewf, deg, cnt, flags, E, N);
  k_dis<<<nbl, 256, 0, stream>>>(deg, N);
  k_block_sums<<<nbl, 256, 0, stream>>>(cnt, bsum, N);
  k_scan_partials<<<1, 512, 0, stream>>>(bsum, nbl);
  k_scan_final<<<nbl, 256, 0, stream>>>(cnt, bsum, rowptr, N, E);
  k_copy_int<<<nbl, 256, 0, stream>>>(rowptr, cnt, N);   // cnt becomes fill cursor
  k_fill<<<ebl, 256, 0, stream>>>(ei, ewf, deg, cnt, col, wv, flags, E, N);

  k_x2a<<<(N*64 + 255)/256, 256, 0, stream>>>(x, A, N*64, flags);

  int pbl = (N + 3)/4;
  int mbl = (N + 63)/64;
  for (int l = 0; l < 4; l++){
    k_prop<<<pbl, 256, 0, stream>>>(rowptr, col, wv, A, (const bf16*)0, B, 1.f, N);
    k_prop<<<pbl, 256, 0, stream>>>(rowptr, col, wv, B, A, C, 2.f, N);
    k_mm3<<<mbl, 256, 0, stream>>>(A, B, C, wlf + (long long)l*12288, blf + (long long)l*64, A, N);
  }
  k_readout<<<pbl, 256, 0, stream>>>(A, batch, wr1f, br1f, wr2f, br2f, gsum, gcnt, flags, N, G);
  k_finalize<<<1, 256, 0, stream>>>(gsum, gcnt, d_out, G, flags);
}

// Round 6
// 1435.379 us; speedup vs baseline: 1.4863x; 1.4863x over previous
//

#include <hip/hip_runtime.h>
#include <hip/hip_bf16.h>

// Round 6: fix k_readout atomic serialization (781us of 2133us total).
// 200k same-address global atomics -> r[N] scratch + hierarchical pooling.
// Construct set kept identical to round 5 (the first build that ran):
// plain kernels, hip_bf16.h, LDS reductions, no templates/lambdas/shuffles.

typedef __hip_bfloat16 bf16;

static __device__ float bf2f(bf16 v){ return __bfloat162float(v); }

// float loader over maybe-bf16 / maybe-f32 data (flag 1 = bf16)
static __device__ float ldany(const void* p, long long i, int isbf){
  if (isbf) return __bfloat162float(((const bf16*)p)[i]);
  return ((const float*)p)[i];
}
// int loader over maybe-int64 / maybe-int32 data (flag 1 = int64)
static __device__ int ldidx(const void* p, long long i, int is64){
  if (is64) return (int)((const long long*)p)[i];
  return ((const int*)p)[i];
}

// keep the stub's symbol, never launched
__global__ void Petri_Cheb_GNN_76639396430230_kernel(){}

// ---- utility ---------------------------------------------------------------

__global__ void k_zero(int* p, int n){
  int i = blockIdx.x*256 + threadIdx.x;
  if (i < n) p[i] = 0;
}

// flags[0] = indices are int64; flags[1] = float tensors are bf16
__global__ void k_detect(const void* ei, const void* x, int N, int* flags){
  if (threadIdx.x != 0 || blockIdx.x != 0) return;
  const int* e32 = (const int*)ei;
  int is64 = 1;
  for (int t = 0; t < 64; t++){
    int lo = e32[2*t], hi = e32[2*t+1];
    if (!(hi == 0 && lo >= 0 && lo < N)){ is64 = 0; break; }
  }
  flags[0] = is64;
  const unsigned short* xh = (const unsigned short*)x;
  int isbf = 1;
  for (int t = 0; t < 128; t++){
    unsigned u = ((unsigned)xh[t]) << 16;
    float v;
    __builtin_memcpy(&v, &u, 4);
    if (!(v == v) || fabsf(v) > 64.f){ isbf = 0; break; }
  }
  flags[1] = isbf;
}

// convert maybe-bf16 tensor to f32 scratch
__global__ void k_cvt(const void* src, float* dst, int n, const int* flags){
  int i = blockIdx.x*256 + threadIdx.x;
  if (i < n) dst[i] = ldany(src, i, flags[1]);
}

// convert input x to bf16 feature buffer
__global__ void k_x2a(const void* x, bf16* a, int n, const int* flags){
  int i = blockIdx.x*256 + threadIdx.x;
  if (i < n) a[i] = __float2bfloat16(ldany(x, i, flags[1]));
}

// ---- CSR build -------------------------------------------------------------

__global__ void k_deg_cnt(const void* ei, const float* ewf, float* deg, int* cnt,
                          const int* flags, int E, int N){
  int e = blockIdx.x*256 + threadIdx.x;
  if (e >= E) return;
  int is64 = flags[0];
  int s = ldidx(ei, e, is64);
  int t = ldidx(ei, (long long)E + e, is64);
  if (s >= 0 && s < N) atomicAdd(&deg[s], ewf[e]);
  if (t >= 0 && t < N) atomicAdd(&cnt[t], 1);
}

__global__ void k_dis(float* deg, int N){
  int i = blockIdx.x*256 + threadIdx.x;
  if (i >= N) return;
  float d = deg[i];
  deg[i] = (d > 0.f) ? rsqrtf(d) : 0.f;   // deg now holds D^{-1/2}
}

__global__ void k_block_sums(const int* cnt, int* bsum, int N){
  __shared__ int s[256];
  int t = threadIdx.x;
  int i = blockIdx.x*256 + t;
  s[t] = (i < N) ? cnt[i] : 0;
  __syncthreads();
  for (int o = 128; o > 0; o >>= 1){
    if (t < o) s[t] += s[t + o];
    __syncthreads();
  }
  if (t == 0) bsum[blockIdx.x] = s[0];
}

__global__ void k_scan_partials(int* bsum, int nb){
  __shared__ int s[512];
  int t = threadIdx.x;
  s[t] = (t < nb) ? bsum[t] : 0;
  __syncthreads();
  for (int o = 1; o < 512; o <<= 1){
    int v = (t >= o) ? s[t - o] : 0;
    __syncthreads();
    s[t] += v;
    __syncthreads();
  }
  if (t < nb) bsum[t] = (t == 0) ? 0 : s[t - 1];   // exclusive prefix
}

__global__ void k_scan_final(const int* cnt, const int* bsum, int* rowptr, int N, int E){
  __shared__ int s[256];
  int t = threadIdx.x;
  int i = blockIdx.x*256 + t;
  int v = (i < N) ? cnt[i] : 0;
  s[t] = v;
  __syncthreads();
  for (int o = 1; o < 256; o <<= 1){
    int u = (t >= o) ? s[t - o] : 0;
    __syncthreads();
    s[t] += u;
    __syncthreads();
  }
  if (i < N) rowptr[i] = s[t] - v + bsum[blockIdx.x];
  if (i == 0) rowptr[N] = E;
}

__global__ void k_copy_int(const int* a, int* b, int n){
  int i = blockIdx.x*256 + threadIdx.x;
  if (i < n) b[i] = a[i];
}

__global__ void k_fill(const void* ei, const float* ewf, const float* dis, int* nxt,
                       int* col, float* wv, const int* flags, int E, int N){
  int e = blockIdx.x*256 + threadIdx.x;
  if (e >= E) return;
  int is64 = flags[0];
  int s = ldidx(ei, e, is64);
  int t = ldidx(ei, (long long)E + e, is64);
  if (s < 0 || s >= N || t < 0 || t >= N) return;
  float w = -dis[s] * ewf[e] * dis[t];
  int p = atomicAdd(&nxt[t], 1);
  if (p >= 0 && p < E){ col[p] = s; wv[p] = w; }
}

// ---- propagation: hout[v][f] = alpha*sum_e wv[e]*hin[col[e]][f] (- sub[v][f])

__global__ void k_prop(const int* rowptr, const int* col, const float* wv,
                       const bf16* hin, const bf16* sub, bf16* hout,
                       float alpha, int N){
  int v = blockIdx.x*4 + (threadIdx.x >> 6);
  if (v >= N) return;
  int lane = threadIdx.x & 63;
  int beg = rowptr[v], end = rowptr[v+1];
  float a0 = 0.f, a1 = 0.f;
  int e = beg;
  for (; e + 2 <= end; e += 2){
    int   s0 = col[e],   s1 = col[e+1];
    float w0 = wv[e],    w1 = wv[e+1];
    float h0 = bf2f(hin[(long long)s0*64 + lane]);
    float h1 = bf2f(hin[(long long)s1*64 + lane]);
    a0 = fmaf(w0, h0, a0);
    a1 = fmaf(w1, h1, a1);
  }
  if (e < end) a0 = fmaf(wv[e], bf2f(hin[(long long)col[e]*64 + lane]), a0);
  float r = alpha * (a0 + a1);
  if (sub) r -= bf2f(sub[(long long)v*64 + lane]);
  hout[(long long)v*64 + lane] = __float2bfloat16(r);
}

// ---- fused 3-matmul: out[n][h] = bias[h] + sum_c sum_k Tc[n][k]*W[c][k][h]

__global__ void k_mm3(const bf16* T0, const bf16* T1, const bf16* T2,
                      const float* W, const float* bias, bf16* out, int N){
  __shared__ float Tn[64*65];
  __shared__ float Wc[64*64];
  int tid = threadIdx.x;
  int tx = tid & 15, ty = tid >> 4;
  int n0 = blockIdx.x * 64;
  float acc[4][4];
  for (int i = 0; i < 4; i++)
    for (int j = 0; j < 4; j++) acc[i][j] = 0.f;
  for (int c = 0; c < 3; c++){
    const bf16* Tm = (c == 0) ? T0 : ((c == 1) ? T1 : T2);
    for (int j = 0; j < 16; j++){
      int idx = tid + j*256;
      int r = idx >> 6, kk = idx & 63;
      int row = n0 + r;
      Tn[r*65 + kk] = (row < N) ? bf2f(Tm[(long long)row*64 + kk]) : 0.f;
      Wc[idx] = W[c*4096 + idx];
    }
    __syncthreads();
    for (int k = 0; k < 64; k++){
      float a0 = Tn[(ty*4+0)*65 + k];
      float a1 = Tn[(ty*4+1)*65 + k];
      float a2 = Tn[(ty*4+2)*65 + k];
      float a3 = Tn[(ty*4+3)*65 + k];
      float b0 = Wc[k*64 + tx*4 + 0];
      float b1 = Wc[k*64 + tx*4 + 1];
      float b2 = Wc[k*64 + tx*4 + 2];
      float b3 = Wc[k*64 + tx*4 + 3];
      acc[0][0] = fmaf(a0,b0,acc[0][0]); acc[0][1] = fmaf(a0,b1,acc[0][1]);
      acc[0][2] = fmaf(a0,b2,acc[0][2]); acc[0][3] = fmaf(a0,b3,acc[0][3]);
      acc[1][0] = fmaf(a1,b0,acc[1][0]); acc[1][1] = fmaf(a1,b1,acc[1][1]);
      acc[1][2] = fmaf(a1,b2,acc[1][2]); acc[1][3] = fmaf(a1,b3,acc[1][3]);
      acc[2][0] = fmaf(a2,b0,acc[2][0]); acc[2][1] = fmaf(a2,b1,acc[2][1]);
      acc[2][2] = fmaf(a2,b2,acc[2][2]); acc[2][3] = fmaf(a2,b3,acc[2][3]);
      acc[3][0] = fmaf(a3,b0,acc[3][0]); acc[3][1] = fmaf(a3,b1,acc[3][1]);
      acc[3][2] = fmaf(a3,b2,acc[3][2]); acc[3][3] = fmaf(a3,b3,acc[3][3]);
    }
    __syncthreads();
  }
  for (int i2 = 0; i2 < 4; i2++){
    int row = n0 + ty*4 + i2;
    if (row < N){
      for (int j = 0; j < 4; j++)
        out[(long long)row*64 + tx*4 + j] = __float2bfloat16(acc[i2][j] + bias[tx*4 + j]);
    }
  }
}

// ---- readout: per-node MLP scalar r[v], NO atomics -------------------------

__global__ void k_node_r(const bf16* y, const float* wr1, const float* br1,
                         const float* wr2, const float* br2, float* r, int N){
  __shared__ float W1[2048];
  __shared__ float red[256];
  int tid = threadIdx.x;
  for (int j = tid; j < 2048; j += 256) W1[j] = wr1[j];
  __syncthreads();
  int v    = blockIdx.x*4 + (tid >> 6);
  int lane = tid & 63;
  int h    = lane & 31;
  int p0   = lane >> 5;
  float acc = 0.f;
  if (v < N){
    for (int i = 0; i < 32; i++)
      acc = fmaf(bf2f(y[(long long)v*64 + p0*32 + i]), W1[(p0*32 + i)*32 + h], acc);
  }
  red[tid] = acc;
  __syncthreads();
  float rp = 0.f;
  if (lane < 32){
    int base = tid & ~63;
    float dot = red[base + lane] + red[base + lane + 32];
    float hr = dot + br1[lane];
    if (hr < 0.f) hr = 0.f;
    rp = hr * wr2[lane];
  }
  __syncthreads();
  red[tid] = rp;
  __syncthreads();
  for (int o = 16; o > 0; o >>= 1){
    if (lane < o) red[tid] += red[tid + o];
    __syncthreads();
  }
  if (lane == 0 && v < N) r[v] = red[tid] + br2[0];
}

// ---- pooling: run-length accumulate over sorted batch -> LDS -> few globals

__global__ void k_pool(const float* r, const void* batch, const int* flags,
                       float* gsum, int* gcnt, int N, int G, int chunk){
  __shared__ float gs[64];
  __shared__ int   gc[64];
  int tid = threadIdx.x;
  if (tid < 64){ gs[tid] = 0.f; gc[tid] = 0; }
  __syncthreads();
  int is64 = flags[0];
  long long beg = (long long)blockIdx.x * chunk;
  long long end = beg + chunk;
  if (end > N) end = N;
  float s = 0.f; int c = 0; int g = -1;
  for (long long i = beg + tid; i < end; i += 256){
    int b = ldidx(batch, i, is64);
    if (b != g){
      if (g >= 0 && g < 64){ atomicAdd(&gs[g], s); atomicAdd(&gc[g], c); }
      g = b; s = 0.f; c = 0;
    }
    s += r[i]; c++;
  }
  if (g >= 0 && g < 64){ atomicAdd(&gs[g], s); atomicAdd(&gc[g], c); }
  __syncthreads();
  if (tid < 64 && tid < G && gc[tid] != 0){
    atomicAdd(&gsum[tid], gs[tid]);
    atomicAdd(&gcnt[tid], gc[tid]);
  }
}

// write result; 30000 sentinel distinguishes "ran but dead" from "never ran"
__global__ void k_finalize(const float* gsum, const int* gcnt, void* out, int G,
                           const int* flags){
  __shared__ float mx;
  if (threadIdx.x == 0){
    float m = 0.f;
    for (int g = 0; g < G; g++){
      float a = gsum[g]; if (a < 0.f) a = -a;
      if (a > m) m = a;
    }
    mx = m;
  }
  __syncthreads();
  int g = threadIdx.x;
  if (g >= G) return;
  float c = (float)gcnt[g];
  if (c < 1.f) c = 1.f;
  float val = (mx > 0.f) ? (gsum[g] / c) : 30000.f;
  if (flags[1]) ((bf16*)out)[g] = __float2bfloat16(val);
  else          ((float*)out)[g] = val;
}

// ---- launch ----------------------------------------------------------------

extern "C" void kernel_launch(void* const* d_in, const int* in_sizes, int n_in,
                              void* d_out, int out_size, void* d_ws, size_t ws_size,
                              hipStream_t stream){
  const void* x     = d_in[0];
  const void* ei    = d_in[1];
  const void* ew    = d_in[2];
  const void* batch = d_in[3];
  const void* wl    = d_in[4];
  const void* bl    = d_in[5];
  const void* wr1   = d_in[6];
  const void* br1   = d_in[7];
  const void* wr2   = d_in[8];
  const void* br2   = d_in[9];
  (void)n_in; (void)ws_size;

  int N = in_sizes[3];
  int E = in_sizes[2];
  int G = out_size;

  // workspace layout (256B aligned), bf16 features: ~60 MB total
  char* p = (char*)d_ws;
  int* flags = (int*)p;                 p += 256;
  float* ewf = (float*)p;               p += (((size_t)E*4 + 255) / 256) * 256;
  float* wf  = (float*)p;               p += (51712*4 + 255) / 256 * 256;
  int* col   = (int*)p;                 p += (((size_t)E*4 + 255) / 256) * 256;
  float* wv  = (float*)p;               p += (((size_t)E*4 + 255) / 256) * 256;
  int* rowptr= (int*)p;                 p += (((size_t)(N+1)*4 + 255) / 256) * 256;
  int* cnt   = (int*)p;                 p += (((size_t)N*4 + 255) / 256) * 256;
  float* deg = (float*)p;               p += (((size_t)N*4 + 255) / 256) * 256;
  int* bsum  = (int*)p;                 p += 4096;
  float* gsum= (float*)p;               p += 1024;
  int* gcnt  = (int*)p;                 p += 1024;
  float* rnode=(float*)p;               p += (((size_t)N*4 + 255) / 256) * 256;
  bf16* A    = (bf16*)p;                p += (((size_t)N*64*2 + 255) / 256) * 256;
  bf16* B    = (bf16*)p;                p += (((size_t)N*64*2 + 255) / 256) * 256;
  bf16* C    = (bf16*)p;                p += (((size_t)N*64*2 + 255) / 256) * 256;

  float* wlf  = wf;           // 49152
  float* blf  = wlf + 49152;  // 256
  float* wr1f = blf + 256;    // 2048
  float* br1f = wr1f + 2048;  // 32
  float* wr2f = br1f + 32;    // 32
  float* br2f = wr2f + 32;    // 1

  int ebl = (E + 255)/256;
  int nbl = (N + 255)/256;

  k_detect<<<1, 64, 0, stream>>>(ei, x, N, flags);
  k_zero<<<nbl, 256, 0, stream>>>((int*)deg, N);
  k_zero<<<nbl, 256, 0, stream>>>(cnt, N);
  k_zero<<<1, 256, 0, stream>>>((int*)gsum, 256);
  k_zero<<<1, 256, 0, stream>>>(gcnt, 256);

  k_cvt<<<ebl, 256, 0, stream>>>(ew, ewf, E, flags);
  k_cvt<<<192, 256, 0, stream>>>(wl, wlf, 49152, flags);
  k_cvt<<<1, 256, 0, stream>>>(bl, blf, 256, flags);
  k_cvt<<<8, 256, 0, stream>>>(wr1, wr1f, 2048, flags);
  k_cvt<<<1, 256, 0, stream>>>(br1, br1f, 32, flags);
  k_cvt<<<1, 256, 0, stream>>>(wr2, wr2f, 32, flags);
  k_cvt<<<1, 256, 0, stream>>>(br2, br2f, 1, flags);

  k_deg_cnt<<<ebl, 256, 0, stream>>>(ei, ewf, deg, cnt, flags, E, N);
  k_dis<<<nbl, 256, 0, stream>>>(deg, N);
  k_block_sums<<<nbl, 256, 0, stream>>>(cnt, bsum, N);
  k_scan_partials<<<1, 512, 0, stream>>>(bsum, nbl);
  k_scan_final<<<nbl, 256, 0, stream>>>(cnt, bsum, rowptr, N, E);
  k_copy_int<<<nbl, 256, 0, stream>>>(rowptr, cnt, N);   // cnt becomes fill cursor
  k_fill<<<ebl, 256, 0, stream>>>(ei, ewf, deg, cnt, col, wv, flags, E, N);

  k_x2a<<<(N*64 + 255)/256, 256, 0, stream>>>(x, A, N*64, flags);

  int pbl = (N + 3)/4;
  int mbl = (N + 63)/64;
  for (int l = 0; l < 4; l++){
    k_prop<<<pbl, 256, 0, stream>>>(rowptr, col, wv, A, (const bf16*)0, B, 1.f, N);
    k_prop<<<pbl, 256, 0, stream>>>(rowptr, col, wv, B, A, C, 2.f, N);
    k_mm3<<<mbl, 256, 0, stream>>>(A, B, C, wlf + (long long)l*12288, blf + (long long)l*64, A, N);
  }

  k_node_r<<<pbl, 256, 0, stream>>>(A, wr1f, br1f, wr2f, br2f, rnode, N);
  int chunk = (N + 127)/128;
  k_pool<<<128, 256, 0, stream>>>(rnode, batch, flags, gsum, gcnt, N, G, chunk);
  k_finalize<<<1, 256, 0, stream>>>(gsum, gcnt, d_out, G, flags);
}

// Round 7
// 1123.326 us; speedup vs baseline: 1.8992x; 1.2778x over previous
//

#include <hip/hip_runtime.h>
#include <hip/hip_bf16.h>

// Round 7: attack prop (8x ~90us) + CSR build atomics.
//  - Chebyshev refactor: out = T0(W0-W2) + P1 W1 + P2 (2 W2), P2 = Lhat P1.
//    prop loses sub/alpha; weights fixed up once in k_wfix.
//  - edges packed as int2{col, w_bits}: one 8B meta load per edge.
//  - prop: 2 lane-groups x 2-unroll = 4 gathers in flight per wave.
//  - k_fill atomics removed via slot trick (slot recorded in k_deg_cnt).
// Construct set identical to round 5/6 (the builds that ran).

typedef __hip_bfloat16 bf16;

static __device__ float bf2f(bf16 v){ return __bfloat162float(v); }

// float loader over maybe-bf16 / maybe-f32 data (flag 1 = bf16)
static __device__ float ldany(const void* p, long long i, int isbf){
  if (isbf) return __bfloat162float(((const bf16*)p)[i]);
  return ((const float*)p)[i];
}
// int loader over maybe-int64 / maybe-int32 data (flag 1 = int64)
static __device__ int ldidx(const void* p, long long i, int is64){
  if (is64) return (int)((const long long*)p)[i];
  return ((const int*)p)[i];
}

// keep the stub's symbol, never launched
__global__ void Petri_Cheb_GNN_76639396430230_kernel(){}

// ---- utility ---------------------------------------------------------------

__global__ void k_zero(int* p, int n){
  int i = blockIdx.x*256 + threadIdx.x;
  if (i < n) p[i] = 0;
}

// flags[0] = indices are int64; flags[1] = float tensors are bf16
__global__ void k_detect(const void* ei, const void* x, int N, int* flags){
  if (threadIdx.x != 0 || blockIdx.x != 0) return;
  const int* e32 = (const int*)ei;
  int is64 = 1;
  for (int t = 0; t < 64; t++){
    int lo = e32[2*t], hi = e32[2*t+1];
    if (!(hi == 0 && lo >= 0 && lo < N)){ is64 = 0; break; }
  }
  flags[0] = is64;
  const unsigned short* xh = (const unsigned short*)x;
  int isbf = 1;
  for (int t = 0; t < 128; t++){
    unsigned u = ((unsigned)xh[t]) << 16;
    float v;
    __builtin_memcpy(&v, &u, 4);
    if (!(v == v) || fabsf(v) > 64.f){ isbf = 0; break; }
  }
  flags[1] = isbf;
}

// convert maybe-bf16 tensor to f32 scratch
__global__ void k_cvt(const void* src, float* dst, int n, const int* flags){
  int i = blockIdx.x*256 + threadIdx.x;
  if (i < n) dst[i] = ldany(src, i, flags[1]);
}

// Chebyshev weight fixup: W0 -= W2; W2 *= 2  (per layer)
__global__ void k_wfix(float* wlf){
  int i = blockIdx.x*256 + threadIdx.x;
  if (i >= 16384) return;                 // 4 layers * 4096
  int l = i >> 12, idx = i & 4095;
  float* Wl = wlf + l*12288;
  float w0 = Wl[idx], w2 = Wl[2*4096 + idx];
  Wl[idx] = w0 - w2;
  Wl[2*4096 + idx] = 2.f * w2;
}

// convert input x to bf16 feature buffer
__global__ void k_x2a(const void* x, bf16* a, int n, const int* flags){
  int i = blockIdx.x*256 + threadIdx.x;
  if (i < n) a[i] = __float2bfloat16(ldany(x, i, flags[1]));
}

// ---- CSR build -------------------------------------------------------------

// deg histogram (by src) + cnt histogram (by tgt) + slot recording
__global__ void k_deg_cnt(const void* ei, const void* ew, float* deg, int* cnt,
                          int* slot, const int* flags, int E, int N){
  int e = blockIdx.x*256 + threadIdx.x;
  if (e >= E) return;
  int is64 = flags[0];
  int s = ldidx(ei, e, is64);
  int t = ldidx(ei, (long long)E + e, is64);
  float w = ldany(ew, e, flags[1]);
  if (s >= 0 && s < N) atomicAdd(&deg[s], w);
  if (t >= 0 && t < N) slot[e] = atomicAdd(&cnt[t], 1);
}

__global__ void k_dis(float* deg, int N){
  int i = blockIdx.x*256 + threadIdx.x;
  if (i >= N) return;
  float d = deg[i];
  deg[i] = (d > 0.f) ? rsqrtf(d) : 0.f;   // deg now holds D^{-1/2}
}

__global__ void k_block_sums(const int* cnt, int* bsum, int N){
  __shared__ int s[256];
  int t = threadIdx.x;
  int i = blockIdx.x*256 + t;
  s[t] = (i < N) ? cnt[i] : 0;
  __syncthreads();
  for (int o = 128; o > 0; o >>= 1){
    if (t < o) s[t] += s[t + o];
    __syncthreads();
  }
  if (t == 0) bsum[blockIdx.x] = s[0];
}

__global__ void k_scan_partials(int* bsum, int nb){
  __shared__ int s[512];
  int t = threadIdx.x;
  s[t] = (t < nb) ? bsum[t] : 0;
  __syncthreads();
  for (int o = 1; o < 512; o <<= 1){
    int v = (t >= o) ? s[t - o] : 0;
    __syncthreads();
    s[t] += v;
    __syncthreads();
  }
  if (t < nb) bsum[t] = (t == 0) ? 0 : s[t - 1];   // exclusive prefix
}

__global__ void k_scan_final(const int* cnt, const int* bsum, int* rowptr, int N, int E){
  __shared__ int s[256];
  int t = threadIdx.x;
  int i = blockIdx.x*256 + t;
  int v = (i < N) ? cnt[i] : 0;
  s[t] = v;
  __syncthreads();
  for (int o = 1; o < 256; o <<= 1){
    int u = (t >= o) ? s[t - o] : 0;
    __syncthreads();
    s[t] += u;
    __syncthreads();
  }
  if (i < N) rowptr[i] = s[t] - v + bsum[blockIdx.x];
  if (i == 0) rowptr[N] = E;
}

// place edges into CSR without atomics: pos = rowptr[t] + slot[e]
__global__ void k_place(const void* ei, const void* ew, const float* dis,
                        const int* rowptr, const int* slot, int2* edges,
                        const int* flags, int E, int N){
  int e = blockIdx.x*256 + threadIdx.x;
  if (e >= E) return;
  int is64 = flags[0];
  int s = ldidx(ei, e, is64);
  int t = ldidx(ei, (long long)E + e, is64);
  if (s < 0 || s >= N || t < 0 || t >= N) return;
  float w = -dis[s] * ldany(ew, e, flags[1]) * dis[t];
  int pos = rowptr[t] + slot[e];
  if (pos >= 0 && pos < E){
    int wb;
    __builtin_memcpy(&wb, &w, 4);
    int2 m; m.x = s; m.y = wb;
    edges[pos] = m;
  }
}

// ---- propagation: hout[v][:] = sum_{e in row v} w[e] * hin[col[e]][:] ------
// wave per node; 2 lane-groups of 32 each own half the row's edges; each lane
// covers a bf16x2 feature pair; 2-unroll -> 4 gathers in flight per wave.

__global__ void k_prop(const int* rowptr, const int2* edges,
                       const bf16* hin, bf16* hout, int N){
  __shared__ float2 sm[256];
  int tid  = threadIdx.x;
  int v    = blockIdx.x*4 + (tid >> 6);
  int lane = tid & 63;
  int g    = lane >> 5;       // edge-group 0/1
  int c    = lane & 31;       // feature pair: features 2c, 2c+1
  int beg = 0, end = 0;
  if (v < N){ beg = rowptr[v]; end = rowptr[v+1]; }
  int cnt  = end - beg;
  int half = (cnt + 1) >> 1;
  int bg = beg + g*half;
  int eg = g ? end : (beg + half);
  const unsigned short* hp = (const unsigned short*)hin;
  float ax = 0.f, ay = 0.f, bx = 0.f, by = 0.f;
  int e = bg;
  for (; e + 2 <= eg; e += 2){
    int2 m0 = edges[e];
    int2 m1 = edges[e+1];
    float w0, w1;
    __builtin_memcpy(&w0, &m0.y, 4);
    __builtin_memcpy(&w1, &m1.y, 4);
    unsigned v0 = *(const unsigned*)(hp + (((long long)m0.x) << 6) + 2*c);
    unsigned v1 = *(const unsigned*)(hp + (((long long)m1.x) << 6) + 2*c);
    unsigned t0 = v0 << 16, t1 = v0 & 0xffff0000u;
    unsigned t2 = v1 << 16, t3 = v1 & 0xffff0000u;
    float h0l, h0h, h1l, h1h;
    __builtin_memcpy(&h0l, &t0, 4); __builtin_memcpy(&h0h, &t1, 4);
    __builtin_memcpy(&h1l, &t2, 4); __builtin_memcpy(&h1h, &t3, 4);
    ax = fmaf(w0, h0l, ax); ay = fmaf(w0, h0h, ay);
    bx = fmaf(w1, h1l, bx); by = fmaf(w1, h1h, by);
  }
  if (e < eg){
    int2 m0 = edges[e];
    float w0;
    __builtin_memcpy(&w0, &m0.y, 4);
    unsigned v0 = *(const unsigned*)(hp + (((long long)m0.x) << 6) + 2*c);
    unsigned t0 = v0 << 16, t1 = v0 & 0xffff0000u;
    float h0l, h0h;
    __builtin_memcpy(&h0l, &t0, 4); __builtin_memcpy(&h0h, &t1, 4);
    ax = fmaf(w0, h0l, ax); ay = fmaf(w0, h0h, ay);
  }
  float2 a; a.x = ax + bx; a.y = ay + by;
  sm[tid] = a;
  __syncthreads();
  if (g == 0 && v < N){
    float2 o = sm[tid];
    float2 q = sm[tid + 32];
    float r0 = o.x + q.x, r1 = o.y + q.y;
    unsigned u0, u1;
    __builtin_memcpy(&u0, &r0, 4);
    __builtin_memcpy(&u1, &r1, 4);
    u0 += 0x7FFFu + ((u0 >> 16) & 1u);      // RNE to bf16
    u1 += 0x7FFFu + ((u1 >> 16) & 1u);
    unsigned pk = (u1 & 0xffff0000u) | (u0 >> 16);
    *(unsigned*)((unsigned short*)hout + (((long long)v) << 6) + 2*c) = pk;
  }
}

// ---- fused 3-matmul: out[n][h] = bias[h] + sum_c sum_k Tc[n][k]*W[c][k][h]

__global__ void k_mm3(const bf16* T0, const bf16* T1, const bf16* T2,
                      const float* W, const float* bias, bf16* out, int N){
  __shared__ float Tn[64*65];
  __shared__ float Wc[64*64];
  int tid = threadIdx.x;
  int tx = tid & 15, ty = tid >> 4;
  int n0 = blockIdx.x * 64;
  float acc[4][4];
  for (int i = 0; i < 4; i++)
    for (int j = 0; j < 4; j++) acc[i][j] = 0.f;
  for (int c = 0; c < 3; c++){
    const bf16* Tm = (c == 0) ? T0 : ((c == 1) ? T1 : T2);
    for (int j = 0; j < 16; j++){
      int idx = tid + j*256;
      int r = idx >> 6, kk = idx & 63;
      int row = n0 + r;
      Tn[r*65 + kk] = (row < N) ? bf2f(Tm[(long long)row*64 + kk]) : 0.f;
      Wc[idx] = W[c*4096 + idx];
    }
    __syncthreads();
    for (int k = 0; k < 64; k++){
      float a0 = Tn[(ty*4+0)*65 + k];
      float a1 = Tn[(ty*4+1)*65 + k];
      float a2 = Tn[(ty*4+2)*65 + k];
      float a3 = Tn[(ty*4+3)*65 + k];
      float b0 = Wc[k*64 + tx*4 + 0];
      float b1 = Wc[k*64 + tx*4 + 1];
      float b2 = Wc[k*64 + tx*4 + 2];
      float b3 = Wc[k*64 + tx*4 + 3];
      acc[0][0] = fmaf(a0,b0,acc[0][0]); acc[0][1] = fmaf(a0,b1,acc[0][1]);
      acc[0][2] = fmaf(a0,b2,acc[0][2]); acc[0][3] = fmaf(a0,b3,acc[0][3]);
      acc[1][0] = fmaf(a1,b0,acc[1][0]); acc[1][1] = fmaf(a1,b1,acc[1][1]);
      acc[1][2] = fmaf(a1,b2,acc[1][2]); acc[1][3] = fmaf(a1,b3,acc[1][3]);
      acc[2][0] = fmaf(a2,b0,acc[2][0]); acc[2][1] = fmaf(a2,b1,acc[2][1]);
      acc[2][2] = fmaf(a2,b2,acc[2][2]); acc[2][3] = fmaf(a2,b3,acc[2][3]);
      acc[3][0] = fmaf(a3,b0,acc[3][0]); acc[3][1] = fmaf(a3,b1,acc[3][1]);
      acc[3][2] = fmaf(a3,b2,acc[3][2]); acc[3][3] = fmaf(a3,b3,acc[3][3]);
    }
    __syncthreads();
  }
  for (int i2 = 0; i2 < 4; i2++){
    int row = n0 + ty*4 + i2;
    if (row < N){
      for (int j = 0; j < 4; j++)
        out[(long long)row*64 + tx*4 + j] = __float2bfloat16(acc[i2][j] + bias[tx*4 + j]);
    }
  }
}

// ---- readout: per-node MLP scalar r[v], no atomics -------------------------

__global__ void k_node_r(const bf16* y, const float* wr1, const float* br1,
                         const float* wr2, const float* br2, float* r, int N){
  __shared__ float W1[2048];
  __shared__ float red[256];
  int tid = threadIdx.x;
  for (int j = tid; j < 2048; j += 256) W1[j] = wr1[j];
  __syncthreads();
  int v    = blockIdx.x*4 + (tid >> 6);
  int lane = tid & 63;
  int h    = lane & 31;
  int p0   = lane >> 5;
  float acc = 0.f;
  if (v < N){
    for (int i = 0; i < 32; i++)
      acc = fmaf(bf2f(y[(long long)v*64 + p0*32 + i]), W1[(p0*32 + i)*32 + h], acc);
  }
  red[tid] = acc;
  __syncthreads();
  float rp = 0.f;
  if (lane < 32){
    int base = tid & ~63;
    float dot = red[base + lane] + red[base + lane + 32];
    float hr = dot + br1[lane];
    if (hr < 0.f) hr = 0.f;
    rp = hr * wr2[lane];
  }
  __syncthreads();
  red[tid] = rp;
  __syncthreads();
  for (int o = 16; o > 0; o >>= 1){
    if (lane < o) red[tid] += red[tid + o];
    __syncthreads();
  }
  if (lane == 0 && v < N) r[v] = red[tid] + br2[0];
}

// ---- pooling: run-length accumulate over sorted batch -> LDS -> few globals

__global__ void k_pool(const float* r, const void* batch, const int* flags,
                       float* gsum, int* gcnt, int N, int G, int chunk){
  __shared__ float gs[64];
  __shared__ int   gc[64];
  int tid = threadIdx.x;
  if (tid < 64){ gs[tid] = 0.f; gc[tid] = 0; }
  __syncthreads();
  int is64 = flags[0];
  long long beg = (long long)blockIdx.x * chunk;
  long long end = beg + chunk;
  if (end > N) end = N;
  float s = 0.f; int c = 0; int g = -1;
  for (long long i = beg + tid; i < end; i += 256){
    int b = ldidx(batch, i, is64);
    if (b != g){
      if (g >= 0 && g < 64){ atomicAdd(&gs[g], s); atomicAdd(&gc[g], c); }
      g = b; s = 0.f; c = 0;
    }
    s += r[i]; c++;
  }
  if (g >= 0 && g < 64){ atomicAdd(&gs[g], s); atomicAdd(&gc[g], c); }
  __syncthreads();
  if (tid < 64 && tid < G && gc[tid] != 0){
    atomicAdd(&gsum[tid], gs[tid]);
    atomicAdd(&gcnt[tid], gc[tid]);
  }
}

// write result; 30000 sentinel distinguishes "ran but dead" from "never ran"
__global__ void k_finalize(const float* gsum, const int* gcnt, void* out, int G,
                           const int* flags){
  __shared__ float mx;
  if (threadIdx.x == 0){
    float m = 0.f;
    for (int g = 0; g < G; g++){
      float a = gsum[g]; if (a < 0.f) a = -a;
      if (a > m) m = a;
    }
    mx = m;
  }
  __syncthreads();
  int g = threadIdx.x;
  if (g >= G) return;
  float c = (float)gcnt[g];
  if (c < 1.f) c = 1.f;
  float val = (mx > 0.f) ? (gsum[g] / c) : 30000.f;
  if (flags[1]) ((bf16*)out)[g] = __float2bfloat16(val);
  else          ((float*)out)[g] = val;
}

// ---- launch ----------------------------------------------------------------

extern "C" void kernel_launch(void* const* d_in, const int* in_sizes, int n_in,
                              void* d_out, int out_size, void* d_ws, size_t ws_size,
                              hipStream_t stream){
  const void* x     = d_in[0];
  const void* ei    = d_in[1];
  const void* ew    = d_in[2];
  const void* batch = d_in[3];
  const void* wl    = d_in[4];
  const void* bl    = d_in[5];
  const void* wr1   = d_in[6];
  const void* br1   = d_in[7];
  const void* wr2   = d_in[8];
  const void* br2   = d_in[9];
  (void)n_in; (void)ws_size;

  int N = in_sizes[3];
  int E = in_sizes[2];
  int G = out_size;

  // workspace layout (256B aligned): ~60 MB total
  char* p = (char*)d_ws;
  int* flags  = (int*)p;                p += 256;
  float* wf   = (float*)p;              p += (51712*4 + 255) / 256 * 256;
  int* slot   = (int*)p;                p += (((size_t)E*4 + 255) / 256) * 256;
  int2* edges = (int2*)p;               p += (((size_t)E*8 + 255) / 256) * 256;
  int* rowptr = (int*)p;                p += (((size_t)(N+1)*4 + 255) / 256) * 256;
  int* cnt    = (int*)p;                p += (((size_t)N*4 + 255) / 256) * 256;
  float* deg  = (float*)p;              p += (((size_t)N*4 + 255) / 256) * 256;
  int* bsum   = (int*)p;                p += 4096;
  float* gsum = (float*)p;              p += 1024;
  int* gcnt   = (int*)p;                p += 1024;
  float* rnode= (float*)p;              p += (((size_t)N*4 + 255) / 256) * 256;
  bf16* A     = (bf16*)p;               p += (((size_t)N*64*2 + 255) / 256) * 256;
  bf16* B     = (bf16*)p;               p += (((size_t)N*64*2 + 255) / 256) * 256;
  bf16* C     = (bf16*)p;               p += (((size_t)N*64*2 + 255) / 256) * 256;

  float* wlf  = wf;           // 49152 (fixed up by k_wfix)
  float* blf  = wlf + 49152;  // 256
  float* wr1f = blf + 256;    // 2048
  float* br1f = wr1f + 2048;  // 32
  float* wr2f = br1f + 32;    // 32
  float* br2f = wr2f + 32;    // 1

  int ebl = (E + 255)/256;
  int nbl = (N + 255)/256;

  k_detect<<<1, 64, 0, stream>>>(ei, x, N, flags);
  k_zero<<<nbl, 256, 0, stream>>>((int*)deg, N);
  k_zero<<<nbl, 256, 0, stream>>>(cnt, N);
  k_zero<<<1, 256, 0, stream>>>((int*)gsum, 256);
  k_zero<<<1, 256, 0, stream>>>(gcnt, 256);

  k_cvt<<<192, 256, 0, stream>>>(wl, wlf, 49152, flags);
  k_cvt<<<1, 256, 0, stream>>>(bl, blf, 256, flags);
  k_cvt<<<8, 256, 0, stream>>>(wr1, wr1f, 2048, flags);
  k_cvt<<<1, 256, 0, stream>>>(br1, br1f, 32, flags);
  k_cvt<<<1, 256, 0, stream>>>(wr2, wr2f, 32, flags);
  k_cvt<<<1, 256, 0, stream>>>(br2, br2f, 1, flags);
  k_wfix<<<64, 256, 0, stream>>>(wlf);

  k_deg_cnt<<<ebl, 256, 0, stream>>>(ei, ew, deg, cnt, slot, flags, E, N);
  k_dis<<<nbl, 256, 0, stream>>>(deg, N);
  k_block_sums<<<nbl, 256, 0, stream>>>(cnt, bsum, N);
  k_scan_partials<<<1, 512, 0, stream>>>(bsum, nbl);
  k_scan_final<<<nbl, 256, 0, stream>>>(cnt, bsum, rowptr, N, E);
  k_place<<<ebl, 256, 0, stream>>>(ei, ew, deg, rowptr, slot, edges, flags, E, N);

  k_x2a<<<(N*64 + 255)/256, 256, 0, stream>>>(x, A, N*64, flags);

  int pbl = (N + 3)/4;
  int mbl = (N + 63)/64;
  for (int l = 0; l < 4; l++){
    k_prop<<<pbl, 256, 0, stream>>>(rowptr, edges, A, B, N);   // P1 = Lhat T0
    k_prop<<<pbl, 256, 0, stream>>>(rowptr, edges, B, C, N);   // P2 = Lhat P1
    k_mm3<<<mbl, 256, 0, stream>>>(A, B, C, wlf + (long long)l*12288, blf + (long long)l*64, A, N);
  }

  k_node_r<<<pbl, 256, 0, stream>>>(A, wr1f, br1f, wr2f, br2f, rnode, N);
  int chunk = (N + 127)/128;
  k_pool<<<128, 256, 0, stream>>>(rnode, batch, flags, gsum, gcnt, N, G, chunk);
  k_finalize<<<1, 256, 0, stream>>>(gsum, gcnt, d_out, G, flags);
}

// Round 8
// 928.667 us; speedup vs baseline: 2.2973x; 1.2096x over previous
//

#include <hip/hip_runtime.h>
#include <hip/hip_bf16.h>

// Round 8: k_mm3 -> bf16 MFMA (v_mfma_f32_16x16x32_bf16).
//  - k_wprep: transposed bf16 weights Wt[l][c][h][k] with Chebyshev fold
//    (W0-W2, W1, 2*W2) replacing k_cvt(wl)+k_wfix.
//  - mm3: 64x64 tile/block, 4 waves, A+Wt staged in LDS (stride-200 ushort
//    rows = 400B: 16B aligned, 2-way bank aliasing = free), 6 K-steps x
//    4 h-tiles per wave, f32 accum, bias epilogue.
// Everything else byte-identical to round 7 (proven). No host API calls in
// kernel_launch (rounds 0-4 that used hipMemsetAsync never executed).

typedef __hip_bfloat16 bf16;
typedef short short8 __attribute__((ext_vector_type(8)));
typedef float floatx4 __attribute__((ext_vector_type(4)));

static __device__ float bf2f(bf16 v){ return __bfloat162float(v); }

// float loader over maybe-bf16 / maybe-f32 data (flag 1 = bf16)
static __device__ float ldany(const void* p, long long i, int isbf){
  if (isbf) return __bfloat162float(((const bf16*)p)[i]);
  return ((const float*)p)[i];
}
// int loader over maybe-int64 / maybe-int32 data (flag 1 = int64)
static __device__ int ldidx(const void* p, long long i, int is64){
  if (is64) return (int)((const long long*)p)[i];
  return ((const int*)p)[i];
}

// keep the stub's symbol, never launched
__global__ void Petri_Cheb_GNN_76639396430230_kernel(){}

// ---- utility ---------------------------------------------------------------

__global__ void k_zero(int* p, int n){
  int i = blockIdx.x*256 + threadIdx.x;
  if (i < n) p[i] = 0;
}

// flags[0] = indices are int64; flags[1] = float tensors are bf16
__global__ void k_detect(const void* ei, const void* x, int N, int* flags){
  if (threadIdx.x != 0 || blockIdx.x != 0) return;
  const int* e32 = (const int*)ei;
  int is64 = 1;
  for (int t = 0; t < 64; t++){
    int lo = e32[2*t], hi = e32[2*t+1];
    if (!(hi == 0 && lo >= 0 && lo < N)){ is64 = 0; break; }
  }
  flags[0] = is64;
  const unsigned short* xh = (const unsigned short*)x;
  int isbf = 1;
  for (int t = 0; t < 128; t++){
    unsigned u = ((unsigned)xh[t]) << 16;
    float v;
    __builtin_memcpy(&v, &u, 4);
    if (!(v == v) || fabsf(v) > 64.f){ isbf = 0; break; }
  }
  flags[1] = isbf;
}

// convert maybe-bf16 tensor to f32 scratch
__global__ void k_cvt(const void* src, float* dst, int n, const int* flags){
  int i = blockIdx.x*256 + threadIdx.x;
  if (i < n) dst[i] = ldany(src, i, flags[1]);
}

// transposed bf16 weights with Chebyshev fold:
// Wt[l][c][h][k]: c0 = W0-W2, c1 = W1, c2 = 2*W2   (orig W[l][c][k][h])
__global__ void k_wprep(const void* wl, bf16* Wt, const int* flags){
  int i = blockIdx.x*256 + threadIdx.x;
  if (i >= 16384) return;                 // 4 layers * 64k * 64h
  int l = i >> 12, j = i & 4095;
  int k = j >> 6, h = j & 63;
  long long base = (long long)l*12288;
  float w0 = ldany(wl, base + 0*4096 + j, flags[1]);
  float w1 = ldany(wl, base + 1*4096 + j, flags[1]);
  float w2 = ldany(wl, base + 2*4096 + j, flags[1]);
  long long dst = (long long)l*12288 + (long long)h*64 + k;
  Wt[dst + 0*4096] = __float2bfloat16(w0 - w2);
  Wt[dst + 1*4096] = __float2bfloat16(w1);
  Wt[dst + 2*4096] = __float2bfloat16(2.f * w2);
}

// convert input x to bf16 feature buffer
__global__ void k_x2a(const void* x, bf16* a, int n, const int* flags){
  int i = blockIdx.x*256 + threadIdx.x;
  if (i < n) a[i] = __float2bfloat16(ldany(x, i, flags[1]));
}

// ---- CSR build -------------------------------------------------------------

__global__ void k_deg_cnt(const void* ei, const void* ew, float* deg, int* cnt,
                          int* slot, const int* flags, int E, int N){
  int e = blockIdx.x*256 + threadIdx.x;
  if (e >= E) return;
  int is64 = flags[0];
  int s = ldidx(ei, e, is64);
  int t = ldidx(ei, (long long)E + e, is64);
  float w = ldany(ew, e, flags[1]);
  if (s >= 0 && s < N) atomicAdd(&deg[s], w);
  if (t >= 0 && t < N) slot[e] = atomicAdd(&cnt[t], 1);
}

__global__ void k_dis(float* deg, int N){
  int i = blockIdx.x*256 + threadIdx.x;
  if (i >= N) return;
  float d = deg[i];
  deg[i] = (d > 0.f) ? rsqrtf(d) : 0.f;   // deg now holds D^{-1/2}
}

__global__ void k_block_sums(const int* cnt, int* bsum, int N){
  __shared__ int s[256];
  int t = threadIdx.x;
  int i = blockIdx.x*256 + t;
  s[t] = (i < N) ? cnt[i] : 0;
  __syncthreads();
  for (int o = 128; o > 0; o >>= 1){
    if (t < o) s[t] += s[t + o];
    __syncthreads();
  }
  if (t == 0) bsum[blockIdx.x] = s[0];
}

__global__ void k_scan_partials(int* bsum, int nb){
  __shared__ int s[512];
  int t = threadIdx.x;
  s[t] = (t < nb) ? bsum[t] : 0;
  __syncthreads();
  for (int o = 1; o < 512; o <<= 1){
    int v = (t >= o) ? s[t - o] : 0;
    __syncthreads();
    s[t] += v;
    __syncthreads();
  }
  if (t < nb) bsum[t] = (t == 0) ? 0 : s[t - 1];   // exclusive prefix
}

__global__ void k_scan_final(const int* cnt, const int* bsum, int* rowptr, int N, int E){
  __shared__ int s[256];
  int t = threadIdx.x;
  int i = blockIdx.x*256 + t;
  int v = (i < N) ? cnt[i] : 0;
  s[t] = v;
  __syncthreads();
  for (int o = 1; o < 256; o <<= 1){
    int u = (t >= o) ? s[t - o] : 0;
    __syncthreads();
    s[t] += u;
    __syncthreads();
  }
  if (i < N) rowptr[i] = s[t] - v + bsum[blockIdx.x];
  if (i == 0) rowptr[N] = E;
}

// place edges into CSR without atomics: pos = rowptr[t] + slot[e]
__global__ void k_place(const void* ei, const void* ew, const float* dis,
                        const int* rowptr, const int* slot, int2* edges,
                        const int* flags, int E, int N){
  int e = blockIdx.x*256 + threadIdx.x;
  if (e >= E) return;
  int is64 = flags[0];
  int s = ldidx(ei, e, is64);
  int t = ldidx(ei, (long long)E + e, is64);
  if (s < 0 || s >= N || t < 0 || t >= N) return;
  float w = -dis[s] * ldany(ew, e, flags[1]) * dis[t];
  int pos = rowptr[t] + slot[e];
  if (pos >= 0 && pos < E){
    int wb;
    __builtin_memcpy(&wb, &w, 4);
    int2 m; m.x = s; m.y = wb;
    edges[pos] = m;
  }
}

// ---- propagation: hout[v][:] = sum_{e in row v} w[e] * hin[col[e]][:] ------

__global__ void k_prop(const int* rowptr, const int2* edges,
                       const bf16* hin, bf16* hout, int N){
  __shared__ float2 sm[256];
  int tid  = threadIdx.x;
  int v    = blockIdx.x*4 + (tid >> 6);
  int lane = tid & 63;
  int g    = lane >> 5;       // edge-group 0/1
  int c    = lane & 31;       // feature pair: features 2c, 2c+1
  int beg = 0, end = 0;
  if (v < N){ beg = rowptr[v]; end = rowptr[v+1]; }
  int cnt  = end - beg;
  int half = (cnt + 1) >> 1;
  int bg = beg + g*half;
  int eg = g ? end : (beg + half);
  const unsigned short* hp = (const unsigned short*)hin;
  float ax = 0.f, ay = 0.f, bx = 0.f, by = 0.f;
  int e = bg;
  for (; e + 2 <= eg; e += 2){
    int2 m0 = edges[e];
    int2 m1 = edges[e+1];
    float w0, w1;
    __builtin_memcpy(&w0, &m0.y, 4);
    __builtin_memcpy(&w1, &m1.y, 4);
    unsigned v0 = *(const unsigned*)(hp + (((long long)m0.x) << 6) + 2*c);
    unsigned v1 = *(const unsigned*)(hp + (((long long)m1.x) << 6) + 2*c);
    unsigned t0 = v0 << 16, t1 = v0 & 0xffff0000u;
    unsigned t2 = v1 << 16, t3 = v1 & 0xffff0000u;
    float h0l, h0h, h1l, h1h;
    __builtin_memcpy(&h0l, &t0, 4); __builtin_memcpy(&h0h, &t1, 4);
    __builtin_memcpy(&h1l, &t2, 4); __builtin_memcpy(&h1h, &t3, 4);
    ax = fmaf(w0, h0l, ax); ay = fmaf(w0, h0h, ay);
    bx = fmaf(w1, h1l, bx); by = fmaf(w1, h1h, by);
  }
  if (e < eg){
    int2 m0 = edges[e];
    float w0;
    __builtin_memcpy(&w0, &m0.y, 4);
    unsigned v0 = *(const unsigned*)(hp + (((long long)m0.x) << 6) + 2*c);
    unsigned t0 = v0 << 16, t1 = v0 & 0xffff0000u;
    float h0l, h0h;
    __builtin_memcpy(&h0l, &t0, 4); __builtin_memcpy(&h0h, &t1, 4);
    ax = fmaf(w0, h0l, ax); ay = fmaf(w0, h0h, ay);
  }
  float2 a; a.x = ax + bx; a.y = ay + by;
  sm[tid] = a;
  __syncthreads();
  if (g == 0 && v < N){
    float2 o = sm[tid];
    float2 q = sm[tid + 32];
    float r0 = o.x + q.x, r1 = o.y + q.y;
    unsigned u0, u1;
    __builtin_memcpy(&u0, &r0, 4);
    __builtin_memcpy(&u1, &r1, 4);
    u0 += 0x7FFFu + ((u0 >> 16) & 1u);      // RNE to bf16
    u1 += 0x7FFFu + ((u1 >> 16) & 1u);
    unsigned pk = (u1 & 0xffff0000u) | (u0 >> 16);
    *(unsigned*)((unsigned short*)hout + (((long long)v) << 6) + 2*c) = pk;
  }
}

// ---- fused 3-matmul via MFMA: out[n][h] = bias[h] + sum_k Acat[n][k]*W[k][h]
// Acat = [T0|T1|T2] (K=192), Wt is bf16 [c][h][k] (pre-transposed, folded).
// 64 nodes x 64 h per block; 4 waves; wave w owns nodes [w*16, w*16+16).

__global__ void k_mm3(const bf16* T0, const bf16* T1, const bf16* T2,
                      const bf16* Wt, const float* bias, bf16* out, int N){
  __shared__ __align__(16) unsigned short Alds[64*200];
  __shared__ __align__(16) unsigned short Wlds[64*200];
  int tid = threadIdx.x;
  int n0 = blockIdx.x * 64;
  // stage: 64 rows x 192 bf16 each for A-concat and Wt (1536 16B chunks each)
  for (int j = 0; j < 6; j++){
    int chunk = tid + j*256;          // 0..1535
    int row    = chunk / 24;
    int within = chunk % 24;
    int c = within >> 3;
    int q = within & 7;
    const bf16* Tm = (c == 0) ? T0 : ((c == 1) ? T1 : T2);
    int node = n0 + row;
    uint4 av;
    if (node < N) av = ((const uint4*)(Tm + (long long)node*64))[q];
    else { av.x = 0; av.y = 0; av.z = 0; av.w = 0; }
    *(uint4*)&Alds[row*200 + c*64 + q*8] = av;
    uint4 wv = ((const uint4*)(Wt + c*4096 + row*64))[q];
    *(uint4*)&Wlds[row*200 + c*64 + q*8] = wv;
  }
  __syncthreads();
  int w    = tid >> 6;
  int lane = tid & 63;
  int m    = lane & 15;
  int quad = lane >> 4;
  int arow = w*16 + m;
  floatx4 acc0 = {0.f,0.f,0.f,0.f};
  floatx4 acc1 = {0.f,0.f,0.f,0.f};
  floatx4 acc2 = {0.f,0.f,0.f,0.f};
  floatx4 acc3 = {0.f,0.f,0.f,0.f};
  for (int kb = 0; kb < 6; kb++){
    int ko = kb*32 + quad*8;
    short8 a  = *(const short8*)&Alds[arow*200 + ko];
    short8 b0 = *(const short8*)&Wlds[( 0 + m)*200 + ko];
    short8 b1 = *(const short8*)&Wlds[(16 + m)*200 + ko];
    short8 b2 = *(const short8*)&Wlds[(32 + m)*200 + ko];
    short8 b3 = *(const short8*)&Wlds[(48 + m)*200 + ko];
    acc0 = __builtin_amdgcn_mfma_f32_16x16x32_bf16(a, b0, acc0, 0, 0, 0);
    acc1 = __builtin_amdgcn_mfma_f32_16x16x32_bf16(a, b1, acc1, 0, 0, 0);
    acc2 = __builtin_amdgcn_mfma_f32_16x16x32_bf16(a, b2, acc2, 0, 0, 0);
    acc3 = __builtin_amdgcn_mfma_f32_16x16x32_bf16(a, b3, acc3, 0, 0, 0);
  }
  // C/D map: col = lane&15 (h within tile), row = quad*4 + reg (node in strip)
  for (int r = 0; r < 4; r++){
    int node = n0 + w*16 + quad*4 + r;
    if (node < N){
      long long o = (long long)node*64;
      out[o +  0 + m] = __float2bfloat16(acc0[r] + bias[ 0 + m]);
      out[o + 16 + m] = __float2bfloat16(acc1[r] + bias[16 + m]);
      out[o + 32 + m] = __float2bfloat16(acc2[r] + bias[32 + m]);
      out[o + 48 + m] = __float2bfloat16(acc3[r] + bias[48 + m]);
    }
  }
}

// ---- readout: per-node MLP scalar r[v], no atomics -------------------------

__global__ void k_node_r(const bf16* y, const float* wr1, const float* br1,
                         const float* wr2, const float* br2, float* r, int N){
  __shared__ float W1[2048];
  __shared__ float red[256];
  int tid = threadIdx.x;
  for (int j = tid; j < 2048; j += 256) W1[j] = wr1[j];
  __syncthreads();
  int v    = blockIdx.x*4 + (tid >> 6);
  int lane = tid & 63;
  int h    = lane & 31;
  int p0   = lane >> 5;
  float acc = 0.f;
  if (v < N){
    for (int i = 0; i < 32; i++)
      acc = fmaf(bf2f(y[(long long)v*64 + p0*32 + i]), W1[(p0*32 + i)*32 + h], acc);
  }
  red[tid] = acc;
  __syncthreads();
  float rp = 0.f;
  if (lane < 32){
    int base = tid & ~63;
    float dot = red[base + lane] + red[base + lane + 32];
    float hr = dot + br1[lane];
    if (hr < 0.f) hr = 0.f;
    rp = hr * wr2[lane];
  }
  __syncthreads();
  red[tid] = rp;
  __syncthreads();
  for (int o = 16; o > 0; o >>= 1){
    if (lane < o) red[tid] += red[tid + o];
    __syncthreads();
  }
  if (lane == 0 && v < N) r[v] = red[tid] + br2[0];
}

// ---- pooling: run-length accumulate over sorted batch -> LDS -> few globals

__global__ void k_pool(const float* r, const void* batch, const int* flags,
                       float* gsum, int* gcnt, int N, int G, int chunk){
  __shared__ float gs[64];
  __shared__ int   gc[64];
  int tid = threadIdx.x;
  if (tid < 64){ gs[tid] = 0.f; gc[tid] = 0; }
  __syncthreads();
  int is64 = flags[0];
  long long beg = (long long)blockIdx.x * chunk;
  long long end = beg + chunk;
  if (end > N) end = N;
  float s = 0.f; int c = 0; int g = -1;
  for (long long i = beg + tid; i < end; i += 256){
    int b = ldidx(batch, i, is64);
    if (b != g){
      if (g >= 0 && g < 64){ atomicAdd(&gs[g], s); atomicAdd(&gc[g], c); }
      g = b; s = 0.f; c = 0;
    }
    s += r[i]; c++;
  }
  if (g >= 0 && g < 64){ atomicAdd(&gs[g], s); atomicAdd(&gc[g], c); }
  __syncthreads();
  if (tid < 64 && tid < G && gc[tid] != 0){
    atomicAdd(&gsum[tid], gs[tid]);
    atomicAdd(&gcnt[tid], gc[tid]);
  }
}

// write result; 30000 sentinel distinguishes "ran but dead" from "never ran"
__global__ void k_finalize(const float* gsum, const int* gcnt, void* out, int G,
                           const int* flags){
  __shared__ float mx;
  if (threadIdx.x == 0){
    float m = 0.f;
    for (int g = 0; g < G; g++){
      float a = gsum[g]; if (a < 0.f) a = -a;
      if (a > m) m = a;
    }
    mx = m;
  }
  __syncthreads();
  int g = threadIdx.x;
  if (g >= G) return;
  float c = (float)gcnt[g];
  if (c < 1.f) c = 1.f;
  float val = (mx > 0.f) ? (gsum[g] / c) : 30000.f;
  if (flags[1]) ((bf16*)out)[g] = __float2bfloat16(val);
  else          ((float*)out)[g] = val;
}

// ---- launch ----------------------------------------------------------------

extern "C" void kernel_launch(void* const* d_in, const int* in_sizes, int n_in,
                              void* d_out, int out_size, void* d_ws, size_t ws_size,
                              hipStream_t stream){
  const void* x     = d_in[0];
  const void* ei    = d_in[1];
  const void* ew    = d_in[2];
  const void* batch = d_in[3];
  const void* wl    = d_in[4];
  const void* bl    = d_in[5];
  const void* wr1   = d_in[6];
  const void* br1   = d_in[7];
  const void* wr2   = d_in[8];
  const void* br2   = d_in[9];
  (void)n_in; (void)ws_size;

  int N = in_sizes[3];
  int E = in_sizes[2];
  int G = out_size;

  // workspace layout (256B aligned): ~60 MB total
  char* p = (char*)d_ws;
  int* flags  = (int*)p;                p += 256;
  float* wf   = (float*)p;              p += (51712*4 + 255) / 256 * 256;
  bf16* Wtb   = (bf16*)p;               p += (49152*2 + 255) / 256 * 256;
  int* slot   = (int*)p;                p += (((size_t)E*4 + 255) / 256) * 256;
  int2* edges = (int2*)p;               p += (((size_t)E*8 + 255) / 256) * 256;
  int* rowptr = (int*)p;                p += (((size_t)(N+1)*4 + 255) / 256) * 256;
  int* cnt    = (int*)p;                p += (((size_t)N*4 + 255) / 256) * 256;
  float* deg  = (float*)p;              p += (((size_t)N*4 + 255) / 256) * 256;
  int* bsum   = (int*)p;                p += 4096;
  float* gsum = (float*)p;              p += 1024;
  int* gcnt   = (int*)p;                p += 1024;
  float* rnode= (float*)p;              p += (((size_t)N*4 + 255) / 256) * 256;
  bf16* A     = (bf16*)p;               p += (((size_t)N*64*2 + 255) / 256) * 256;
  bf16* B     = (bf16*)p;               p += (((size_t)N*64*2 + 255) / 256) * 256;
  bf16* C     = (bf16*)p;               p += (((size_t)N*64*2 + 255) / 256) * 256;

  float* blf  = wf + 49152;   // 256   (wf head region unused now)
  float* wr1f = blf + 256;    // 2048
  float* br1f = wr1f + 2048;  // 32
  float* wr2f = br1f + 32;    // 32
  float* br2f = wr2f + 32;    // 1

  int ebl = (E + 255)/256;
  int nbl = (N + 255)/256;

  k_detect<<<1, 64, 0, stream>>>(ei, x, N, flags);
  k_zero<<<nbl, 256, 0, stream>>>((int*)deg, N);
  k_zero<<<nbl, 256, 0, stream>>>(cnt, N);
  k_zero<<<1, 256, 0, stream>>>((int*)gsum, 256);
  k_zero<<<1, 256, 0, stream>>>(gcnt, 256);

  k_wprep<<<64, 256, 0, stream>>>(wl, Wtb, flags);
  k_cvt<<<1, 256, 0, stream>>>(bl, blf, 256, flags);
  k_cvt<<<8, 256, 0, stream>>>(wr1, wr1f, 2048, flags);
  k_cvt<<<1, 256, 0, stream>>>(br1, br1f, 32, flags);
  k_cvt<<<1, 256, 0, stream>>>(wr2, wr2f, 32, flags);
  k_cvt<<<1, 256, 0, stream>>>(br2, br2f, 1, flags);

  k_deg_cnt<<<ebl, 256, 0, stream>>>(ei, ew, deg, cnt, slot, flags, E, N);
  k_dis<<<nbl, 256, 0, stream>>>(deg, N);
  k_block_sums<<<nbl, 256, 0, stream>>>(cnt, bsum, N);
  k_scan_partials<<<1, 512, 0, stream>>>(bsum, nbl);
  k_scan_final<<<nbl, 256, 0, stream>>>(cnt, bsum, rowptr, N, E);
  k_place<<<ebl, 256, 0, stream>>>(ei, ew, deg, rowptr, slot, edges, flags, E, N);

  k_x2a<<<(N*64 + 255)/256, 256, 0, stream>>>(x, A, N*64, flags);

  int pbl = (N + 3)/4;
  int mbl = (N + 63)/64;
  for (int l = 0; l < 4; l++){
    k_prop<<<pbl, 256, 0, stream>>>(rowptr, edges, A, B, N);   // P1 = Lhat T0
    k_prop<<<pbl, 256, 0, stream>>>(rowptr, edges, B, C, N);   // P2 = Lhat P1
    k_mm3<<<mbl, 256, 0, stream>>>(A, B, C, Wtb + (long long)l*12288,
                                   blf + (long long)l*64, A, N);
  }

  k_node_r<<<pbl, 256, 0, stream>>>(A, wr1f, br1f, wr2f, br2f, rnode, N);
  int chunk = (N + 127)/128;
  k_pool<<<128, 256, 0, stream>>>(rnode, batch, flags, gsum, gcnt, N, G, chunk);
  k_finalize<<<1, 256, 0, stream>>>(gsum, gcnt, d_out, G, flags);
}

// Round 9
// 805.824 us; speedup vs baseline: 2.6476x; 1.1524x over previous
//

#include <hip/hip_runtime.h>
#include <hip/hip_bf16.h>

// Round 9: k_prop MLP boost. 2 groups x 2 unroll (4 gathers in flight) ->
// 4 groups x 16 lanes x 8B + 2 unroll (8 in flight). Same bytes/edge.
// Everything else byte-identical to round 8 (929us, absmax 0).

typedef __hip_bfloat16 bf16;
typedef short short8 __attribute__((ext_vector_type(8)));
typedef float floatx4 __attribute__((ext_vector_type(4)));

static __device__ float bf2f(bf16 v){ return __bfloat162float(v); }

// float loader over maybe-bf16 / maybe-f32 data (flag 1 = bf16)
static __device__ float ldany(const void* p, long long i, int isbf){
  if (isbf) return __bfloat162float(((const bf16*)p)[i]);
  return ((const float*)p)[i];
}
// int loader over maybe-int64 / maybe-int32 data (flag 1 = int64)
static __device__ int ldidx(const void* p, long long i, int is64){
  if (is64) return (int)((const long long*)p)[i];
  return ((const int*)p)[i];
}

// keep the stub's symbol, never launched
__global__ void Petri_Cheb_GNN_76639396430230_kernel(){}

// ---- utility ---------------------------------------------------------------

__global__ void k_zero(int* p, int n){
  int i = blockIdx.x*256 + threadIdx.x;
  if (i < n) p[i] = 0;
}

// flags[0] = indices are int64; flags[1] = float tensors are bf16
__global__ void k_detect(const void* ei, const void* x, int N, int* flags){
  if (threadIdx.x != 0 || blockIdx.x != 0) return;
  const int* e32 = (const int*)ei;
  int is64 = 1;
  for (int t = 0; t < 64; t++){
    int lo = e32[2*t], hi = e32[2*t+1];
    if (!(hi == 0 && lo >= 0 && lo < N)){ is64 = 0; break; }
  }
  flags[0] = is64;
  const unsigned short* xh = (const unsigned short*)x;
  int isbf = 1;
  for (int t = 0; t < 128; t++){
    unsigned u = ((unsigned)xh[t]) << 16;
    float v;
    __builtin_memcpy(&v, &u, 4);
    if (!(v == v) || fabsf(v) > 64.f){ isbf = 0; break; }
  }
  flags[1] = isbf;
}

// convert maybe-bf16 tensor to f32 scratch
__global__ void k_cvt(const void* src, float* dst, int n, const int* flags){
  int i = blockIdx.x*256 + threadIdx.x;
  if (i < n) dst[i] = ldany(src, i, flags[1]);
}

// transposed bf16 weights with Chebyshev fold:
// Wt[l][c][h][k]: c0 = W0-W2, c1 = W1, c2 = 2*W2   (orig W[l][c][k][h])
__global__ void k_wprep(const void* wl, bf16* Wt, const int* flags){
  int i = blockIdx.x*256 + threadIdx.x;
  if (i >= 16384) return;                 // 4 layers * 64k * 64h
  int l = i >> 12, j = i & 4095;
  int k = j >> 6, h = j & 63;
  long long base = (long long)l*12288;
  float w0 = ldany(wl, base + 0*4096 + j, flags[1]);
  float w1 = ldany(wl, base + 1*4096 + j, flags[1]);
  float w2 = ldany(wl, base + 2*4096 + j, flags[1]);
  long long dst = (long long)l*12288 + (long long)h*64 + k;
  Wt[dst + 0*4096] = __float2bfloat16(w0 - w2);
  Wt[dst + 1*4096] = __float2bfloat16(w1);
  Wt[dst + 2*4096] = __float2bfloat16(2.f * w2);
}

// convert input x to bf16 feature buffer
__global__ void k_x2a(const void* x, bf16* a, int n, const int* flags){
  int i = blockIdx.x*256 + threadIdx.x;
  if (i < n) a[i] = __float2bfloat16(ldany(x, i, flags[1]));
}

// ---- CSR build -------------------------------------------------------------

__global__ void k_deg_cnt(const void* ei, const void* ew, float* deg, int* cnt,
                          int* slot, const int* flags, int E, int N){
  int e = blockIdx.x*256 + threadIdx.x;
  if (e >= E) return;
  int is64 = flags[0];
  int s = ldidx(ei, e, is64);
  int t = ldidx(ei, (long long)E + e, is64);
  float w = ldany(ew, e, flags[1]);
  if (s >= 0 && s < N) atomicAdd(&deg[s], w);
  if (t >= 0 && t < N) slot[e] = atomicAdd(&cnt[t], 1);
}

__global__ void k_dis(float* deg, int N){
  int i = blockIdx.x*256 + threadIdx.x;
  if (i >= N) return;
  float d = deg[i];
  deg[i] = (d > 0.f) ? rsqrtf(d) : 0.f;   // deg now holds D^{-1/2}
}

__global__ void k_block_sums(const int* cnt, int* bsum, int N){
  __shared__ int s[256];
  int t = threadIdx.x;
  int i = blockIdx.x*256 + t;
  s[t] = (i < N) ? cnt[i] : 0;
  __syncthreads();
  for (int o = 128; o > 0; o >>= 1){
    if (t < o) s[t] += s[t + o];
    __syncthreads();
  }
  if (t == 0) bsum[blockIdx.x] = s[0];
}

__global__ void k_scan_partials(int* bsum, int nb){
  __shared__ int s[512];
  int t = threadIdx.x;
  s[t] = (t < nb) ? bsum[t] : 0;
  __syncthreads();
  for (int o = 1; o < 512; o <<= 1){
    int v = (t >= o) ? s[t - o] : 0;
    __syncthreads();
    s[t] += v;
    __syncthreads();
  }
  if (t < nb) bsum[t] = (t == 0) ? 0 : s[t - 1];   // exclusive prefix
}

__global__ void k_scan_final(const int* cnt, const int* bsum, int* rowptr, int N, int E){
  __shared__ int s[256];
  int t = threadIdx.x;
  int i = blockIdx.x*256 + t;
  int v = (i < N) ? cnt[i] : 0;
  s[t] = v;
  __syncthreads();
  for (int o = 1; o < 256; o <<= 1){
    int u = (t >= o) ? s[t - o] : 0;
    __syncthreads();
    s[t] += u;
    __syncthreads();
  }
  if (i < N) rowptr[i] = s[t] - v + bsum[blockIdx.x];
  if (i == 0) rowptr[N] = E;
}

// place edges into CSR without atomics: pos = rowptr[t] + slot[e]
__global__ void k_place(const void* ei, const void* ew, const float* dis,
                        const int* rowptr, const int* slot, int2* edges,
                        const int* flags, int E, int N){
  int e = blockIdx.x*256 + threadIdx.x;
  if (e >= E) return;
  int is64 = flags[0];
  int s = ldidx(ei, e, is64);
  int t = ldidx(ei, (long long)E + e, is64);
  if (s < 0 || s >= N || t < 0 || t >= N) return;
  float w = -dis[s] * ldany(ew, e, flags[1]) * dis[t];
  int pos = rowptr[t] + slot[e];
  if (pos >= 0 && pos < E){
    int wb;
    __builtin_memcpy(&wb, &w, 4);
    int2 m; m.x = s; m.y = wb;
    edges[pos] = m;
  }
}

// ---- propagation: hout[v][:] = sum_{e in row v} w[e] * hin[col[e]][:] ------
// wave per node; 4 edge-groups x 16 lanes; each lane owns features 4c..4c+3
// (8B loads); 2-unroll -> 8 gathers in flight per wave.

__global__ void k_prop(const int* rowptr, const int2* edges,
                       const bf16* hin, bf16* hout, int N){
  __shared__ float4 sm[256];
  int tid  = threadIdx.x;
  int v    = blockIdx.x*4 + (tid >> 6);
  int lane = tid & 63;
  int g    = lane >> 4;       // edge-group 0..3
  int c    = lane & 15;       // feature quad: features 4c..4c+3
  int beg = 0, end = 0;
  if (v < N){ beg = rowptr[v]; end = rowptr[v+1]; }
  int cnt  = end - beg;
  int q    = (cnt + 3) >> 2;
  int bg = beg + g*q;
  int eg = bg + q;
  if (bg > end) bg = end;
  if (eg > end) eg = end;
  const unsigned short* hp = (const unsigned short*)hin;
  float a0=0.f,a1=0.f,a2=0.f,a3=0.f;
  float b0=0.f,b1=0.f,b2=0.f,b3=0.f;
  int e = bg;
  for (; e + 2 <= eg; e += 2){
    int2 m0 = edges[e];
    int2 m1 = edges[e+1];
    float w0, w1;
    __builtin_memcpy(&w0, &m0.y, 4);
    __builtin_memcpy(&w1, &m1.y, 4);
    unsigned long long u0 = *(const unsigned long long*)(hp + (((long long)m0.x) << 6) + 4*c);
    unsigned long long u1 = *(const unsigned long long*)(hp + (((long long)m1.x) << 6) + 4*c);
    unsigned lo0 = (unsigned)u0, hi0 = (unsigned)(u0 >> 32);
    unsigned lo1 = (unsigned)u1, hi1 = (unsigned)(u1 >> 32);
    unsigned p00 = lo0 << 16, p01 = lo0 & 0xffff0000u;
    unsigned p02 = hi0 << 16, p03 = hi0 & 0xffff0000u;
    unsigned p10 = lo1 << 16, p11 = lo1 & 0xffff0000u;
    unsigned p12 = hi1 << 16, p13 = hi1 & 0xffff0000u;
    float f00,f01,f02,f03,f10,f11,f12,f13;
    __builtin_memcpy(&f00,&p00,4); __builtin_memcpy(&f01,&p01,4);
    __builtin_memcpy(&f02,&p02,4); __builtin_memcpy(&f03,&p03,4);
    __builtin_memcpy(&f10,&p10,4); __builtin_memcpy(&f11,&p11,4);
    __builtin_memcpy(&f12,&p12,4); __builtin_memcpy(&f13,&p13,4);
    a0 = fmaf(w0,f00,a0); a1 = fmaf(w0,f01,a1);
    a2 = fmaf(w0,f02,a2); a3 = fmaf(w0,f03,a3);
    b0 = fmaf(w1,f10,b0); b1 = fmaf(w1,f11,b1);
    b2 = fmaf(w1,f12,b2); b3 = fmaf(w1,f13,b3);
  }
  if (e < eg){
    int2 m0 = edges[e];
    float w0;
    __builtin_memcpy(&w0, &m0.y, 4);
    unsigned long long u0 = *(const unsigned long long*)(hp + (((long long)m0.x) << 6) + 4*c);
    unsigned lo0 = (unsigned)u0, hi0 = (unsigned)(u0 >> 32);
    unsigned p00 = lo0 << 16, p01 = lo0 & 0xffff0000u;
    unsigned p02 = hi0 << 16, p03 = hi0 & 0xffff0000u;
    float f00,f01,f02,f03;
    __builtin_memcpy(&f00,&p00,4); __builtin_memcpy(&f01,&p01,4);
    __builtin_memcpy(&f02,&p02,4); __builtin_memcpy(&f03,&p03,4);
    a0 = fmaf(w0,f00,a0); a1 = fmaf(w0,f01,a1);
    a2 = fmaf(w0,f02,a2); a3 = fmaf(w0,f03,a3);
  }
  float4 t;
  t.x = a0 + b0; t.y = a1 + b1; t.z = a2 + b2; t.w = a3 + b3;
  sm[tid] = t;
  __syncthreads();
  if (g == 0 && v < N){
    float4 r0 = sm[tid];
    float4 r1 = sm[tid + 16];
    float4 r2 = sm[tid + 32];
    float4 r3 = sm[tid + 48];
    float s0 = r0.x + r1.x + r2.x + r3.x;
    float s1 = r0.y + r1.y + r2.y + r3.y;
    float s2 = r0.z + r1.z + r2.z + r3.z;
    float s3 = r0.w + r1.w + r2.w + r3.w;
    unsigned u0,u1,u2,u3;
    __builtin_memcpy(&u0,&s0,4); __builtin_memcpy(&u1,&s1,4);
    __builtin_memcpy(&u2,&s2,4); __builtin_memcpy(&u3,&s3,4);
    u0 += 0x7FFFu + ((u0 >> 16) & 1u);     // RNE to bf16
    u1 += 0x7FFFu + ((u1 >> 16) & 1u);
    u2 += 0x7FFFu + ((u2 >> 16) & 1u);
    u3 += 0x7FFFu + ((u3 >> 16) & 1u);
    unsigned pk0 = (u1 & 0xffff0000u) | (u0 >> 16);
    unsigned pk1 = (u3 & 0xffff0000u) | (u2 >> 16);
    unsigned long long pk = ((unsigned long long)pk1 << 32) | pk0;
    *(unsigned long long*)((unsigned short*)hout + (((long long)v) << 6) + 4*c) = pk;
  }
}

// ---- fused 3-matmul via MFMA: out[n][h] = bias[h] + sum_k Acat[n][k]*W[k][h]
// Acat = [T0|T1|T2] (K=192), Wt is bf16 [c][h][k] (pre-transposed, folded).
// 64 nodes x 64 h per block; 4 waves; wave w owns nodes [w*16, w*16+16).

__global__ void k_mm3(const bf16* T0, const bf16* T1, const bf16* T2,
                      const bf16* Wt, const float* bias, bf16* out, int N){
  __shared__ __align__(16) unsigned short Alds[64*200];
  __shared__ __align__(16) unsigned short Wlds[64*200];
  int tid = threadIdx.x;
  int n0 = blockIdx.x * 64;
  // stage: 64 rows x 192 bf16 each for A-concat and Wt (1536 16B chunks each)
  for (int j = 0; j < 6; j++){
    int chunk = tid + j*256;          // 0..1535
    int row    = chunk / 24;
    int within = chunk % 24;
    int c = within >> 3;
    int q = within & 7;
    const bf16* Tm = (c == 0) ? T0 : ((c == 1) ? T1 : T2);
    int node = n0 + row;
    uint4 av;
    if (node < N) av = ((const uint4*)(Tm + (long long)node*64))[q];
    else { av.x = 0; av.y = 0; av.z = 0; av.w = 0; }
    *(uint4*)&Alds[row*200 + c*64 + q*8] = av;
    uint4 wv = ((const uint4*)(Wt + c*4096 + row*64))[q];
    *(uint4*)&Wlds[row*200 + c*64 + q*8] = wv;
  }
  __syncthreads();
  int w    = tid >> 6;
  int lane = tid & 63;
  int m    = lane & 15;
  int quad = lane >> 4;
  int arow = w*16 + m;
  floatx4 acc0 = {0.f,0.f,0.f,0.f};
  floatx4 acc1 = {0.f,0.f,0.f,0.f};
  floatx4 acc2 = {0.f,0.f,0.f,0.f};
  floatx4 acc3 = {0.f,0.f,0.f,0.f};
  for (int kb = 0; kb < 6; kb++){
    int ko = kb*32 + quad*8;
    short8 a  = *(const short8*)&Alds[arow*200 + ko];
    short8 b0 = *(const short8*)&Wlds[( 0 + m)*200 + ko];
    short8 b1 = *(const short8*)&Wlds[(16 + m)*200 + ko];
    short8 b2 = *(const short8*)&Wlds[(32 + m)*200 + ko];
    short8 b3 = *(const short8*)&Wlds[(48 + m)*200 + ko];
    acc0 = __builtin_amdgcn_mfma_f32_16x16x32_bf16(a, b0, acc0, 0, 0, 0);
    acc1 = __builtin_amdgcn_mfma_f32_16x16x32_bf16(a, b1, acc1, 0, 0, 0);
    acc2 = __builtin_amdgcn_mfma_f32_16x16x32_bf16(a, b2, acc2, 0, 0, 0);
    acc3 = __builtin_amdgcn_mfma_f32_16x16x32_bf16(a, b3, acc3, 0, 0, 0);
  }
  // C/D map: col = lane&15 (h within tile), row = quad*4 + reg (node in strip)
  for (int r = 0; r < 4; r++){
    int node = n0 + w*16 + quad*4 + r;
    if (node < N){
      long long o = (long long)node*64;
      out[o +  0 + m] = __float2bfloat16(acc0[r] + bias[ 0 + m]);
      out[o + 16 + m] = __float2bfloat16(acc1[r] + bias[16 + m]);
      out[o + 32 + m] = __float2bfloat16(acc2[r] + bias[32 + m]);
      out[o + 48 + m] = __float2bfloat16(acc3[r] + bias[48 + m]);
    }
  }
}

// ---- readout: per-node MLP scalar r[v], no atomics -------------------------

__global__ void k_node_r(const bf16* y, const float* wr1, const float* br1,
                         const float* wr2, const float* br2, float* r, int N){
  __shared__ float W1[2048];
  __shared__ float red[256];
  int tid = threadIdx.x;
  for (int j = tid; j < 2048; j += 256) W1[j] = wr1[j];
  __syncthreads();
  int v    = blockIdx.x*4 + (tid >> 6);
  int lane = tid & 63;
  int h    = lane & 31;
  int p0   = lane >> 5;
  float acc = 0.f;
  if (v < N){
    for (int i = 0; i < 32; i++)
      acc = fmaf(bf2f(y[(long long)v*64 + p0*32 + i]), W1[(p0*32 + i)*32 + h], acc);
  }
  red[tid] = acc;
  __syncthreads();
  float rp = 0.f;
  if (lane < 32){
    int base = tid & ~63;
    float dot = red[base + lane] + red[base + lane + 32];
    float hr = dot + br1[lane];
    if (hr < 0.f) hr = 0.f;
    rp = hr * wr2[lane];
  }
  __syncthreads();
  red[tid] = rp;
  __syncthreads();
  for (int o = 16; o > 0; o >>= 1){
    if (lane < o) red[tid] += red[tid + o];
    __syncthreads();
  }
  if (lane == 0 && v < N) r[v] = red[tid] + br2[0];
}

// ---- pooling: run-length accumulate over sorted batch -> LDS -> few globals

__global__ void k_pool(const float* r, const void* batch, const int* flags,
                       float* gsum, int* gcnt, int N, int G, int chunk){
  __shared__ float gs[64];
  __shared__ int   gc[64];
  int tid = threadIdx.x;
  if (tid < 64){ gs[tid] = 0.f; gc[tid] = 0; }
  __syncthreads();
  int is64 = flags[0];
  long long beg = (long long)blockIdx.x * chunk;
  long long end = beg + chunk;
  if (end > N) end = N;
  float s = 0.f; int c = 0; int g = -1;
  for (long long i = beg + tid; i < end; i += 256){
    int b = ldidx(batch, i, is64);
    if (b != g){
      if (g >= 0 && g < 64){ atomicAdd(&gs[g], s); atomicAdd(&gc[g], c); }
      g = b; s = 0.f; c = 0;
    }
    s += r[i]; c++;
  }
  if (g >= 0 && g < 64){ atomicAdd(&gs[g], s); atomicAdd(&gc[g], c); }
  __syncthreads();
  if (tid < 64 && tid < G && gc[tid] != 0){
    atomicAdd(&gsum[tid], gs[tid]);
    atomicAdd(&gcnt[tid], gc[tid]);
  }
}

// write result; 30000 sentinel distinguishes "ran but dead" from "never ran"
__global__ void k_finalize(const float* gsum, const int* gcnt, void* out, int G,
                           const int* flags){
  __shared__ float mx;
  if (threadIdx.x == 0){
    float m = 0.f;
    for (int g = 0; g < G; g++){
      float a = gsum[g]; if (a < 0.f) a = -a;
      if (a > m) m = a;
    }
    mx = m;
  }
  __syncthreads();
  int g = threadIdx.x;
  if (g >= G) return;
  float c = (float)gcnt[g];
  if (c < 1.f) c = 1.f;
  float val = (mx > 0.f) ? (gsum[g] / c) : 30000.f;
  if (flags[1]) ((bf16*)out)[g] = __float2bfloat16(val);
  else          ((float*)out)[g] = val;
}

// ---- launch ----------------------------------------------------------------

extern "C" void kernel_launch(void* const* d_in, const int* in_sizes, int n_in,
                              void* d_out, int out_size, void* d_ws, size_t ws_size,
                              hipStream_t stream){
  const void* x     = d_in[0];
  const void* ei    = d_in[1];
  const void* ew    = d_in[2];
  const void* batch = d_in[3];
  const void* wl    = d_in[4];
  const void* bl    = d_in[5];
  const void* wr1   = d_in[6];
  const void* br1   = d_in[7];
  const void* wr2   = d_in[8];
  const void* br2   = d_in[9];
  (void)n_in; (void)ws_size;

  int N = in_sizes[3];
  int E = in_sizes[2];
  int G = out_size;

  // workspace layout (256B aligned): ~60 MB total
  char* p = (char*)d_ws;
  int* flags  = (int*)p;                p += 256;
  float* wf   = (float*)p;              p += (51712*4 + 255) / 256 * 256;
  bf16* Wtb   = (bf16*)p;               p += (49152*2 + 255) / 256 * 256;
  int* slot   = (int*)p;                p += (((size_t)E*4 + 255) / 256) * 256;
  int2* edges = (int2*)p;               p += (((size_t)E*8 + 255) / 256) * 256;
  int* rowptr = (int*)p;                p += (((size_t)(N+1)*4 + 255) / 256) * 256;
  int* cnt    = (int*)p;                p += (((size_t)N*4 + 255) / 256) * 256;
  float* deg  = (float*)p;              p += (((size_t)N*4 + 255) / 256) * 256;
  int* bsum   = (int*)p;                p += 4096;
  float* gsum = (float*)p;              p += 1024;
  int* gcnt   = (int*)p;                p += 1024;
  float* rnode= (float*)p;              p += (((size_t)N*4 + 255) / 256) * 256;
  bf16* A     = (bf16*)p;               p += (((size_t)N*64*2 + 255) / 256) * 256;
  bf16* B     = (bf16*)p;               p += (((size_t)N*64*2 + 255) / 256) * 256;
  bf16* C     = (bf16*)p;               p += (((size_t)N*64*2 + 255) / 256) * 256;

  float* blf  = wf + 49152;   // 256   (wf head region unused now)
  float* wr1f = blf + 256;    // 2048
  float* br1f = wr1f + 2048;  // 32
  float* wr2f = br1f + 32;    // 32
  float* br2f = wr2f + 32;    // 1

  int ebl = (E + 255)/256;
  int nbl = (N + 255)/256;

  k_detect<<<1, 64, 0, stream>>>(ei, x, N, flags);
  k_zero<<<nbl, 256, 0, stream>>>((int*)deg, N);
  k_zero<<<nbl, 256, 0, stream>>>(cnt, N);
  k_zero<<<1, 256, 0, stream>>>((int*)gsum, 256);
  k_zero<<<1, 256, 0, stream>>>(gcnt, 256);

  k_wprep<<<64, 256, 0, stream>>>(wl, Wtb, flags);
  k_cvt<<<1, 256, 0, stream>>>(bl, blf, 256, flags);
  k_cvt<<<8, 256, 0, stream>>>(wr1, wr1f, 2048, flags);
  k_cvt<<<1, 256, 0, stream>>>(br1, br1f, 32, flags);
  k_cvt<<<1, 256, 0, stream>>>(wr2, wr2f, 32, flags);
  k_cvt<<<1, 256, 0, stream>>>(br2, br2f, 1, flags);

  k_deg_cnt<<<ebl, 256, 0, stream>>>(ei, ew, deg, cnt, slot, flags, E, N);
  k_dis<<<nbl, 256, 0, stream>>>(deg, N);
  k_block_sums<<<nbl, 256, 0, stream>>>(cnt, bsum, N);
  k_scan_partials<<<1, 512, 0, stream>>>(bsum, nbl);
  k_scan_final<<<nbl, 256, 0, stream>>>(cnt, bsum, rowptr, N, E);
  k_place<<<ebl, 256, 0, stream>>>(ei, ew, deg, rowptr, slot, edges, flags, E, N);

  k_x2a<<<(N*64 + 255)/256, 256, 0, stream>>>(x, A, N*64, flags);

  int pbl = (N + 3)/4;
  int mbl = (N + 63)/64;
  for (int l = 0; l < 4; l++){
    k_prop<<<pbl, 256, 0, stream>>>(rowptr, edges, A, B, N);   // P1 = Lhat T0
    k_prop<<<pbl, 256, 0, stream>>>(rowptr, edges, B, C, N);   // P2 = Lhat P1
    k_mm3<<<mbl, 256, 0, stream>>>(A, B, C, Wtb + (long long)l*12288,
                                   blf + (long long)l*64, A, N);
  }

  k_node_r<<<pbl, 256, 0, stream>>>(A, wr1f, br1f, wr2f, br2f, rnode, N);
  int chunk = (N + 127)/128;
  k_pool<<<128, 256, 0, stream>>>(rnode, batch, flags, gsum, gcnt, N, G, chunk);
  k_finalize<<<1, 256, 0, stream>>>(gsum, gcnt, d_out, G, flags);
}

// Round 10
// 776.979 us; speedup vs baseline: 2.7458x; 1.0371x over previous
//

#include <hip/hip_runtime.h>
#include <hip/hip_bf16.h>

// Round 10: replace atomic CSR build with bucketed counting sort.
//  - k_deg: src-degree atomics only (1.6M vs 3.2M ops).
//  - k_bhist/k_bscan/k_scan1024/k_scatter/k_csr: atomic-free (global) CSR.
//  - rec aliases A, tloc aliases B (consumed before features exist).
// prop/mm3/readout/pool byte-identical to round 9 (806us, absmax 0.0156).

typedef __hip_bfloat16 bf16;
typedef short short8 __attribute__((ext_vector_type(8)));
typedef float floatx4 __attribute__((ext_vector_type(4)));

static __device__ float bf2f(bf16 v){ return __bfloat162float(v); }

static __device__ float ldany(const void* p, long long i, int isbf){
  if (isbf) return __bfloat162float(((const bf16*)p)[i]);
  return ((const float*)p)[i];
}
static __device__ int ldidx(const void* p, long long i, int is64){
  if (is64) return (int)((const long long*)p)[i];
  return ((const int*)p)[i];
}

// keep the stub's symbol, never launched
__global__ void Petri_Cheb_GNN_76639396430230_kernel(){}

// ---- utility ---------------------------------------------------------------

__global__ void k_zero(int* p, int n){
  int i = blockIdx.x*256 + threadIdx.x;
  if (i < n) p[i] = 0;
}

__global__ void k_detect(const void* ei, const void* x, int N, int* flags){
  if (threadIdx.x != 0 || blockIdx.x != 0) return;
  const int* e32 = (const int*)ei;
  int is64 = 1;
  for (int t = 0; t < 64; t++){
    int lo = e32[2*t], hi = e32[2*t+1];
    if (!(hi == 0 && lo >= 0 && lo < N)){ is64 = 0; break; }
  }
  flags[0] = is64;
  const unsigned short* xh = (const unsigned short*)x;
  int isbf = 1;
  for (int t = 0; t < 128; t++){
    unsigned u = ((unsigned)xh[t]) << 16;
    float v;
    __builtin_memcpy(&v, &u, 4);
    if (!(v == v) || fabsf(v) > 64.f){ isbf = 0; break; }
  }
  flags[1] = isbf;
}

__global__ void k_cvt(const void* src, float* dst, int n, const int* flags){
  int i = blockIdx.x*256 + threadIdx.x;
  if (i < n) dst[i] = ldany(src, i, flags[1]);
}

// transposed bf16 weights with Chebyshev fold:
// Wt[l][c][h][k]: c0 = W0-W2, c1 = W1, c2 = 2*W2   (orig W[l][c][k][h])
__global__ void k_wprep(const void* wl, bf16* Wt, const int* flags){
  int i = blockIdx.x*256 + threadIdx.x;
  if (i >= 16384) return;
  int l = i >> 12, j = i & 4095;
  int k = j >> 6, h = j & 63;
  long long base = (long long)l*12288;
  float w0 = ldany(wl, base + 0*4096 + j, flags[1]);
  float w1 = ldany(wl, base + 1*4096 + j, flags[1]);
  float w2 = ldany(wl, base + 2*4096 + j, flags[1]);
  long long dst = (long long)l*12288 + (long long)h*64 + k;
  Wt[dst + 0*4096] = __float2bfloat16(w0 - w2);
  Wt[dst + 1*4096] = __float2bfloat16(w1);
  Wt[dst + 2*4096] = __float2bfloat16(2.f * w2);
}

__global__ void k_x2a(const void* x, bf16* a, int n, const int* flags){
  int i = blockIdx.x*256 + threadIdx.x;
  if (i < n) a[i] = __float2bfloat16(ldany(x, i, flags[1]));
}

// ---- degree (still atomic; by src) -----------------------------------------

__global__ void k_deg(const void* ei, const void* ew, float* deg,
                      const int* flags, int E, int N){
  int e = blockIdx.x*256 + threadIdx.x;
  if (e >= E) return;
  int s = ldidx(ei, e, flags[0]);
  float w = ldany(ew, e, flags[1]);
  if (s >= 0 && s < N) atomicAdd(&deg[s], w);
}

__global__ void k_dis(float* deg, int N){
  int i = blockIdx.x*256 + threadIdx.x;
  if (i >= N) return;
  float d = deg[i];
  deg[i] = (d > 0.f) ? rsqrtf(d) : 0.f;   // deg now holds D^{-1/2}
}

// ---- bucketed counting sort by target --------------------------------------

// pass 1: per-chunk-block histogram over nbk buckets (bucket = t >> shift)
__global__ void k_bhist(const void* ei, const int* flags, int E, int N,
                        int nbk, int nch, int chunk, int shift, int* hist){
  __shared__ int h[1024];
  int tid = threadIdx.x;
  for (int i = tid; i < nbk; i += 256) h[i] = 0;
  __syncthreads();
  int is64 = flags[0];
  long long b = (long long)blockIdx.x * chunk;
  long long e = b + chunk; if (e > (long long)E) e = (long long)E;
  for (long long i = b + tid; i < e; i += 256){
    int t = ldidx(ei, (long long)E + i, is64);
    if (t >= 0 && t < N) atomicAdd(&h[t >> shift], 1);
  }
  __syncthreads();
  for (int i = tid; i < nbk; i += 256)
    hist[(long long)i*nch + blockIdx.x] = h[i];
}

// pass 2: per bucket, exclusive scan across chunk blocks (in place) + total
__global__ void k_bscan(int* hist, int* btot, int nch){
  __shared__ int s[256];
  int tid = threadIdx.x;
  int* row = hist + (long long)blockIdx.x * nch;
  int k = (nch + 255) / 256;
  int b0 = tid * k;
  int sum = 0;
  for (int j = 0; j < k; j++){
    int idx = b0 + j;
    if (idx < nch) sum += row[idx];
  }
  s[tid] = sum;
  __syncthreads();
  for (int o = 1; o < 256; o <<= 1){
    int v = (tid >= o) ? s[tid - o] : 0;
    __syncthreads();
    s[tid] += v;
    __syncthreads();
  }
  int run = s[tid] - sum;       // exclusive prefix of this thread's stripe
  for (int j = 0; j < k; j++){
    int idx = b0 + j;
    if (idx < nch){ int v = row[idx]; row[idx] = run; run += v; }
  }
  if (tid == 255) btot[blockIdx.x] = s[255];
}

// pass 2b: exclusive scan of bucket totals -> bucket bases (nbk <= 1024)
__global__ void k_scan1024(const int* btot, int* bbase, int nbk){
  __shared__ int s[1024];
  int tid = threadIdx.x;
  int v = (tid < nbk) ? btot[tid] : 0;
  s[tid] = v;
  __syncthreads();
  for (int o = 1; o < 1024; o <<= 1){
    int u = (tid >= o) ? s[tid - o] : 0;
    __syncthreads();
    s[tid] += u;
    __syncthreads();
  }
  if (tid < nbk) bbase[tid] = s[tid] - v;
}

// pass 3: scatter edges into bucket-grouped records via LDS cursors
__global__ void k_scatter(const void* ei, const void* ew, const float* dis,
                          const int* flags, int E, int N, int nbk, int nch,
                          int chunk, int shift,
                          const int* hist, const int* bbase,
                          int2* rec, unsigned short* tloc){
  __shared__ int cur[1024];
  int tid = threadIdx.x;
  for (int i = tid; i < nbk; i += 256)
    cur[i] = bbase[i] + hist[(long long)i*nch + blockIdx.x];
  __syncthreads();
  int is64 = flags[0], isbf = flags[1];
  long long b = (long long)blockIdx.x * chunk;
  long long e = b + chunk; if (e > (long long)E) e = (long long)E;
  unsigned msk = (1u << shift) - 1u;
  for (long long i = b + tid; i < e; i += 256){
    int s = ldidx(ei, i, is64);
    int t = ldidx(ei, (long long)E + i, is64);
    if (s < 0 || s >= N || t < 0 || t >= N) continue;
    float w = -dis[s] * ldany(ew, i, isbf) * dis[t];
    int bk = t >> shift;
    int pos = atomicAdd(&cur[bk], 1);
    int wb; __builtin_memcpy(&wb, &w, 4);
    int2 m; m.x = s; m.y = wb;
    rec[pos] = m;
    tloc[pos] = (unsigned short)(t & msk);
  }
}

// pass 4: per bucket, per-node counts -> rowptr + reorder into final CSR
__global__ void k_csr(const int2* rec, const unsigned short* tloc,
                      const int* btot, const int* bbase,
                      int* rowptr, int2* edges, int N, int E,
                      int shift, int nbk){
  __shared__ int cnt[1024];
  __shared__ int pfx[1024];
  __shared__ int cur[1024];
  int tid = threadIdx.x;
  int bk  = blockIdx.x;
  int bkb = 1 << shift;
  int n0  = bk << shift;
  int nn  = N - n0; if (nn > bkb) nn = bkb;
  for (int i = tid; i < bkb; i += 256) cnt[i] = 0;
  __syncthreads();
  int base = bbase[bk];
  int tot  = btot[bk];
  for (int i = tid; i < tot; i += 256)
    atomicAdd(&cnt[tloc[base + i]], 1);
  __syncthreads();
  if (tid == 0){
    int run = 0;
    for (int i = 0; i < bkb; i++){ pfx[i] = run; cur[i] = run; run += cnt[i]; }
  }
  __syncthreads();
  for (int i = tid; i < nn; i += 256) rowptr[n0 + i] = base + pfx[i];
  if (bk == nbk - 1 && tid == 0) rowptr[N] = base + tot;
  for (int i = tid; i < tot; i += 256){
    int l = tloc[base + i];
    int pos = atomicAdd(&cur[l], 1);
    edges[base + pos] = rec[base + i];
  }
}

// ---- propagation: hout[v][:] = sum_{e in row v} w[e] * hin[col[e]][:] ------

__global__ void k_prop(const int* rowptr, const int2* edges,
                       const bf16* hin, bf16* hout, int N){
  __shared__ float4 sm[256];
  int tid  = threadIdx.x;
  int v    = blockIdx.x*4 + (tid >> 6);
  int lane = tid & 63;
  int g    = lane >> 4;       // edge-group 0..3
  int c    = lane & 15;       // feature quad: features 4c..4c+3
  int beg = 0, end = 0;
  if (v < N){ beg = rowptr[v]; end = rowptr[v+1]; }
  int cnt  = end - beg;
  int q    = (cnt + 3) >> 2;
  int bg = beg + g*q;
  int eg = bg + q;
  if (bg > end) bg = end;
  if (eg > end) eg = end;
  const unsigned short* hp = (const unsigned short*)hin;
  float a0=0.f,a1=0.f,a2=0.f,a3=0.f;
  float b0=0.f,b1=0.f,b2=0.f,b3=0.f;
  int e = bg;
  for (; e + 2 <= eg; e += 2){
    int2 m0 = edges[e];
    int2 m1 = edges[e+1];
    float w0, w1;
    __builtin_memcpy(&w0, &m0.y, 4);
    __builtin_memcpy(&w1, &m1.y, 4);
    unsigned long long u0 = *(const unsigned long long*)(hp + (((long long)m0.x) << 6) + 4*c);
    unsigned long long u1 = *(const unsigned long long*)(hp + (((long long)m1.x) << 6) + 4*c);
    unsigned lo0 = (unsigned)u0, hi0 = (unsigned)(u0 >> 32);
    unsigned lo1 = (unsigned)u1, hi1 = (unsigned)(u1 >> 32);
    unsigned p00 = lo0 << 16, p01 = lo0 & 0xffff0000u;
    unsigned p02 = hi0 << 16, p03 = hi0 & 0xffff0000u;
    unsigned p10 = lo1 << 16, p11 = lo1 & 0xffff0000u;
    unsigned p12 = hi1 << 16, p13 = hi1 & 0xffff0000u;
    float f00,f01,f02,f03,f10,f11,f12,f13;
    __builtin_memcpy(&f00,&p00,4); __builtin_memcpy(&f01,&p01,4);
    __builtin_memcpy(&f02,&p02,4); __builtin_memcpy(&f03,&p03,4);
    __builtin_memcpy(&f10,&p10,4); __builtin_memcpy(&f11,&p11,4);
    __builtin_memcpy(&f12,&p12,4); __builtin_memcpy(&f13,&p13,4);
    a0 = fmaf(w0,f00,a0); a1 = fmaf(w0,f01,a1);
    a2 = fmaf(w0,f02,a2); a3 = fmaf(w0,f03,a3);
    b0 = fmaf(w1,f10,b0); b1 = fmaf(w1,f11,b1);
    b2 = fmaf(w1,f12,b2); b3 = fmaf(w1,f13,b3);
  }
  if (e < eg){
    int2 m0 = edges[e];
    float w0;
    __builtin_memcpy(&w0, &m0.y, 4);
    unsigned long long u0 = *(const unsigned long long*)(hp + (((long long)m0.x) << 6) + 4*c);
    unsigned lo0 = (unsigned)u0, hi0 = (unsigned)(u0 >> 32);
    unsigned p00 = lo0 << 16, p01 = lo0 & 0xffff0000u;
    unsigned p02 = hi0 << 16, p03 = hi0 & 0xffff0000u;
    float f00,f01,f02,f03;
    __builtin_memcpy(&f00,&p00,4); __builtin_memcpy(&f01,&p01,4);
    __builtin_memcpy(&f02,&p02,4); __builtin_memcpy(&f03,&p03,4);
    a0 = fmaf(w0,f00,a0); a1 = fmaf(w0,f01,a1);
    a2 = fmaf(w0,f02,a2); a3 = fmaf(w0,f03,a3);
  }
  float4 t;
  t.x = a0 + b0; t.y = a1 + b1; t.z = a2 + b2; t.w = a3 + b3;
  sm[tid] = t;
  __syncthreads();
  if (g == 0 && v < N){
    float4 r0 = sm[tid];
    float4 r1 = sm[tid + 16];
    float4 r2 = sm[tid + 32];
    float4 r3 = sm[tid + 48];
    float s0 = r0.x + r1.x + r2.x + r3.x;
    float s1 = r0.y + r1.y + r2.y + r3.y;
    float s2 = r0.z + r1.z + r2.z + r3.z;
    float s3 = r0.w + r1.w + r2.w + r3.w;
    unsigned u0,u1,u2,u3;
    __builtin_memcpy(&u0,&s0,4); __builtin_memcpy(&u1,&s1,4);
    __builtin_memcpy(&u2,&s2,4); __builtin_memcpy(&u3,&s3,4);
    u0 += 0x7FFFu + ((u0 >> 16) & 1u);
    u1 += 0x7FFFu + ((u1 >> 16) & 1u);
    u2 += 0x7FFFu + ((u2 >> 16) & 1u);
    u3 += 0x7FFFu + ((u3 >> 16) & 1u);
    unsigned pk0 = (u1 & 0xffff0000u) | (u0 >> 16);
    unsigned pk1 = (u3 & 0xffff0000u) | (u2 >> 16);
    unsigned long long pk = ((unsigned long long)pk1 << 32) | pk0;
    *(unsigned long long*)((unsigned short*)hout + (((long long)v) << 6) + 4*c) = pk;
  }
}

// ---- fused 3-matmul via MFMA -----------------------------------------------

__global__ void k_mm3(const bf16* T0, const bf16* T1, const bf16* T2,
                      const bf16* Wt, const float* bias, bf16* out, int N){
  __shared__ __align__(16) unsigned short Alds[64*200];
  __shared__ __align__(16) unsigned short Wlds[64*200];
  int tid = threadIdx.x;
  int n0 = blockIdx.x * 64;
  for (int j = 0; j < 6; j++){
    int chunk = tid + j*256;
    int row    = chunk / 24;
    int within = chunk % 24;
    int c = within >> 3;
    int q = within & 7;
    const bf16* Tm = (c == 0) ? T0 : ((c == 1) ? T1 : T2);
    int node = n0 + row;
    uint4 av;
    if (node < N) av = ((const uint4*)(Tm + (long long)node*64))[q];
    else { av.x = 0; av.y = 0; av.z = 0; av.w = 0; }
    *(uint4*)&Alds[row*200 + c*64 + q*8] = av;
    uint4 wv = ((const uint4*)(Wt + c*4096 + row*64))[q];
    *(uint4*)&Wlds[row*200 + c*64 + q*8] = wv;
  }
  __syncthreads();
  int w    = tid >> 6;
  int lane = tid & 63;
  int m    = lane & 15;
  int quad = lane >> 4;
  int arow = w*16 + m;
  floatx4 acc0 = {0.f,0.f,0.f,0.f};
  floatx4 acc1 = {0.f,0.f,0.f,0.f};
  floatx4 acc2 = {0.f,0.f,0.f,0.f};
  floatx4 acc3 = {0.f,0.f,0.f,0.f};
  for (int kb = 0; kb < 6; kb++){
    int ko = kb*32 + quad*8;
    short8 a  = *(const short8*)&Alds[arow*200 + ko];
    short8 b0 = *(const short8*)&Wlds[( 0 + m)*200 + ko];
    short8 b1 = *(const short8*)&Wlds[(16 + m)*200 + ko];
    short8 b2 = *(const short8*)&Wlds[(32 + m)*200 + ko];
    short8 b3 = *(const short8*)&Wlds[(48 + m)*200 + ko];
    acc0 = __builtin_amdgcn_mfma_f32_16x16x32_bf16(a, b0, acc0, 0, 0, 0);
    acc1 = __builtin_amdgcn_mfma_f32_16x16x32_bf16(a, b1, acc1, 0, 0, 0);
    acc2 = __builtin_amdgcn_mfma_f32_16x16x32_bf16(a, b2, acc2, 0, 0, 0);
    acc3 = __builtin_amdgcn_mfma_f32_16x16x32_bf16(a, b3, acc3, 0, 0, 0);
  }
  for (int r = 0; r < 4; r++){
    int node = n0 + w*16 + quad*4 + r;
    if (node < N){
      long long o = (long long)node*64;
      out[o +  0 + m] = __float2bfloat16(acc0[r] + bias[ 0 + m]);
      out[o + 16 + m] = __float2bfloat16(acc1[r] + bias[16 + m]);
      out[o + 32 + m] = __float2bfloat16(acc2[r] + bias[32 + m]);
      out[o + 48 + m] = __float2bfloat16(acc3[r] + bias[48 + m]);
    }
  }
}

// ---- readout: per-node MLP scalar r[v] -------------------------------------

__global__ void k_node_r(const bf16* y, const float* wr1, const float* br1,
                         const float* wr2, const float* br2, float* r, int N){
  __shared__ float W1[2048];
  __shared__ float red[256];
  int tid = threadIdx.x;
  for (int j = tid; j < 2048; j += 256) W1[j] = wr1[j];
  __syncthreads();
  int v    = blockIdx.x*4 + (tid >> 6);
  int lane = tid & 63;
  int h    = lane & 31;
  int p0   = lane >> 5;
  float acc = 0.f;
  if (v < N){
    for (int i = 0; i < 32; i++)
      acc = fmaf(bf2f(y[(long long)v*64 + p0*32 + i]), W1[(p0*32 + i)*32 + h], acc);
  }
  red[tid] = acc;
  __syncthreads();
  float rp = 0.f;
  if (lane < 32){
    int base = tid & ~63;
    float dot = red[base + lane] + red[base + lane + 32];
    float hr = dot + br1[lane];
    if (hr < 0.f) hr = 0.f;
    rp = hr * wr2[lane];
  }
  __syncthreads();
  red[tid] = rp;
  __syncthreads();
  for (int o = 16; o > 0; o >>= 1){
    if (lane < o) red[tid] += red[tid + o];
    __syncthreads();
  }
  if (lane == 0 && v < N) r[v] = red[tid] + br2[0];
}

// ---- pooling ---------------------------------------------------------------

__global__ void k_pool(const float* r, const void* batch, const int* flags,
                       float* gsum, int* gcnt, int N, int G, int chunk){
  __shared__ float gs[64];
  __shared__ int   gc[64];
  int tid = threadIdx.x;
  if (tid < 64){ gs[tid] = 0.f; gc[tid] = 0; }
  __syncthreads();
  int is64 = flags[0];
  long long beg = (long long)blockIdx.x * chunk;
  long long end = beg + chunk;
  if (end > N) end = N;
  float s = 0.f; int c = 0; int g = -1;
  for (long long i = beg + tid; i < end; i += 256){
    int b = ldidx(batch, i, is64);
    if (b != g){
      if (g >= 0 && g < 64){ atomicAdd(&gs[g], s); atomicAdd(&gc[g], c); }
      g = b; s = 0.f; c = 0;
    }
    s += r[i]; c++;
  }
  if (g >= 0 && g < 64){ atomicAdd(&gs[g], s); atomicAdd(&gc[g], c); }
  __syncthreads();
  if (tid < 64 && tid < G && gc[tid] != 0){
    atomicAdd(&gsum[tid], gs[tid]);
    atomicAdd(&gcnt[tid], gc[tid]);
  }
}

__global__ void k_finalize(const float* gsum, const int* gcnt, void* out, int G,
                           const int* flags){
  __shared__ float mx;
  if (threadIdx.x == 0){
    float m = 0.f;
    for (int g = 0; g < G; g++){
      float a = gsum[g]; if (a < 0.f) a = -a;
      if (a > m) m = a;
    }
    mx = m;
  }
  __syncthreads();
  int g = threadIdx.x;
  if (g >= G) return;
  float c = (float)gcnt[g];
  if (c < 1.f) c = 1.f;
  float val = (mx > 0.f) ? (gsum[g] / c) : 30000.f;
  if (flags[1]) ((bf16*)out)[g] = __float2bfloat16(val);
  else          ((float*)out)[g] = val;
}

// ---- launch ----------------------------------------------------------------

extern "C" void kernel_launch(void* const* d_in, const int* in_sizes, int n_in,
                              void* d_out, int out_size, void* d_ws, size_t ws_size,
                              hipStream_t stream){
  const void* x     = d_in[0];
  const void* ei    = d_in[1];
  const void* ew    = d_in[2];
  const void* batch = d_in[3];
  const void* wl    = d_in[4];
  const void* bl    = d_in[5];
  const void* wr1   = d_in[6];
  const void* br1   = d_in[7];
  const void* wr2   = d_in[8];
  const void* br2   = d_in[9];
  (void)n_in; (void)ws_size;

  int N = in_sizes[3];
  int E = in_sizes[2];
  int G = out_size;

  // bucket geometry
  int shift = 7;
  while ((((long long)N + (1 << shift) - 1) >> shift) > 1024) shift++;
  int nbk = (N + (1 << shift) - 1) >> shift;     // <= 1024
  int nch = 784;                                 // chunk blocks
  int chunkE = (E + nch - 1) / nch;

  // feature/records region sizes (rec aliases A, tloc aliases B)
  size_t featB = (size_t)N * 64 * 2;
  size_t recB  = (size_t)E * 8;
  size_t aRegion = featB > recB ? featB : recB;
  size_t tlocB = (size_t)E * 2;
  size_t bRegion = featB > tlocB ? featB : tlocB;

  char* p = (char*)d_ws;
  int* flags  = (int*)p;                p += 256;
  float* wfs  = (float*)p;              p += (2560*4 + 255) / 256 * 256;
  bf16* Wtb   = (bf16*)p;               p += (49152*2 + 255) / 256 * 256;
  int* hist   = (int*)p;                p += (((size_t)nbk*nch*4 + 255) / 256) * 256;
  int* btot   = (int*)p;                p += 4096;
  int* bbase  = (int*)p;                p += 4096;
  int* rowptr = (int*)p;                p += (((size_t)(N+1)*4 + 255) / 256) * 256;
  float* deg  = (float*)p;              p += (((size_t)N*4 + 255) / 256) * 256;
  float* gsum = (float*)p;              p += 1024;
  int* gcnt   = (int*)p;                p += 1024;
  float* rnode= (float*)p;              p += (((size_t)N*4 + 255) / 256) * 256;
  char* aReg  = p;                      p += ((aRegion + 255) / 256) * 256;
  char* bReg  = p;                      p += ((bRegion + 255) / 256) * 256;
  bf16* C     = (bf16*)p;               p += ((featB + 255) / 256) * 256;
  int2* edges = (int2*)p;               p += ((recB + 255) / 256) * 256;

  bf16* A = (bf16*)aReg;
  bf16* B = (bf16*)bReg;
  int2* rec = (int2*)aReg;                  // consumed before A is written
  unsigned short* tloc = (unsigned short*)bReg;  // consumed before B is written

  float* blf  = wfs;          // 256
  float* wr1f = blf + 256;    // 2048
  float* br1f = wr1f + 2048;  // 32
  float* wr2f = br1f + 32;    // 32
  float* br2f = wr2f + 32;    // 1

  int ebl = (E + 255)/256;
  int nbl = (N + 255)/256;

  k_detect<<<1, 64, 0, stream>>>(ei, x, N, flags);
  k_zero<<<nbl, 256, 0, stream>>>((int*)deg, N);
  k_zero<<<1, 256, 0, stream>>>((int*)gsum, 256);
  k_zero<<<1, 256, 0, stream>>>(gcnt, 256);

  k_wprep<<<64, 256, 0, stream>>>(wl, Wtb, flags);
  k_cvt<<<1, 256, 0, stream>>>(bl, blf, 256, flags);
  k_cvt<<<8, 256, 0, stream>>>(wr1, wr1f, 2048, flags);
  k_cvt<<<1, 256, 0, stream>>>(br1, br1f, 32, flags);
  k_cvt<<<1, 256, 0, stream>>>(wr2, wr2f, 32, flags);
  k_cvt<<<1, 256, 0, stream>>>(br2, br2f, 1, flags);

  k_deg<<<ebl, 256, 0, stream>>>(ei, ew, deg, flags, E, N);
  k_dis<<<nbl, 256, 0, stream>>>(deg, N);

  k_bhist<<<nch, 256, 0, stream>>>(ei, flags, E, N, nbk, nch, chunkE, shift, hist);
  k_bscan<<<nbk, 256, 0, stream>>>(hist, btot, nch);
  k_scan1024<<<1, 1024, 0, stream>>>(btot, bbase, nbk);
  k_scatter<<<nch, 256, 0, stream>>>(ei, ew, deg, flags, E, N, nbk, nch,
                                     chunkE, shift, hist, bbase, rec, tloc);
  k_csr<<<nbk, 256, 0, stream>>>(rec, tloc, btot, bbase, rowptr, edges,
                                 N, E, shift, nbk);

  k_x2a<<<(N*64 + 255)/256, 256, 0, stream>>>(x, A, N*64, flags);

  int pbl = (N + 3)/4;
  int mbl = (N + 63)/64;
  for (int l = 0; l < 4; l++){
    k_prop<<<pbl, 256, 0, stream>>>(rowptr, edges, A, B, N);   // P1 = Lhat T0
    k_prop<<<pbl, 256, 0, stream>>>(rowptr, edges, B, C, N);   // P2 = Lhat P1
    k_mm3<<<mbl, 256, 0, stream>>>(A, B, C, Wtb + (long long)l*12288,
                                   blf + (long long)l*64, A, N);
  }

  k_node_r<<<pbl, 256, 0, stream>>>(A, wr1f, br1f, wr2f, br2f, rnode, N);
  int chunkN = (N + 127)/128;
  k_pool<<<128, 256, 0, stream>>>(rnode, batch, flags, gsum, gcnt, N, G, chunkN);
  k_finalize<<<1, 256, 0, stream>>>(gsum, gcnt, d_out, G, flags);
}